// Round 2
// baseline (2561.456 us; speedup 1.0000x reference)
//
#include <hip/hip_runtime.h>
#include <hip/hip_bf16.h>
#include <math.h>

typedef unsigned short u16;
typedef __attribute__((ext_vector_type(4))) float f32x4;
typedef __attribute__((ext_vector_type(8))) __bf16 bf16x8;

#define B_    4
#define NQ_   3136
#define C_    512
#define HIMG  56
#define WIMG  56
#define HD_   4096
#define NK_   784
#define NKP_  896

static __device__ __forceinline__ float b2f(u16 u){
  union { unsigned int i; float f; } v; v.i = ((unsigned int)u)<<16; return v.f;
}
static __device__ __forceinline__ u16 f2b(float f){
  union { float f; unsigned int i; } v; v.f = f;
  unsigned int r = v.i + 0x7fffu + ((v.i>>16)&1u);
  return (u16)(r>>16);
}

#define GLD16(gsrc, ldst) __builtin_amdgcn_global_load_lds( \
    (const __attribute__((address_space(1))) void*)(gsrc), \
    (__attribute__((address_space(3))) void*)(ldst), 16, 0, 0)

// ---------------------------------------------------------------------------
// bf16 GEMM: C[m,n] = (sum_k A[m,k]*B[n,k] + bias1[n]) * hscale * dsc + bias2
// A: (M,K) bf16 row-major stride sA; B: (N,K) bf16 row-major stride sB.
// 128x128 tile, BK=32, 4 waves of 64x64, mfma 16x16x32, global_load_lds w=16.
// A/B loads are NOT masked in M/N (caller guarantees in-ws over-read slack);
// stores masked by row<M only (cols always valid by construction).
// ---------------------------------------------------------------------------
template<int OUT_F32>
__global__ __launch_bounds__(256)
void gemm_bt(const u16* __restrict__ A, const u16* __restrict__ Bm, void* __restrict__ Cm,
             int M, int K, int sA, int sB, int sC, int zdiv,
             long long zA1, long long zA2, long long zB1, long long zB2,
             long long zC1, long long zC2,
             const float* __restrict__ bias1, float hscale,
             const float* __restrict__ scalePtr,
             const float* __restrict__ bias2, int rowsPerB, int b2s)
{
  __shared__ u16 lA[128*32];
  __shared__ u16 lB[128*32];
  const int z  = blockIdx.z;
  const int zq = z / zdiv, zr = z % zdiv;
  const u16* Ab = A  + (long long)zq*zA1 + (long long)zr*zA2;
  const u16* Bb = Bm + (long long)zq*zB1 + (long long)zr*zB2;
  const int m0 = blockIdx.x*128, n0 = blockIdx.y*128;
  const int t = threadIdx.x, wave = t>>6, lane = t&63;
  const int wm = (wave>>1)*64, wn = (wave&1)*64;
  const int lrow = t>>2, lcol = (t&3)*8;

  const u16* aSrc = Ab + (long long)(m0+lrow)*sA + lcol;
  const u16* bSrc = Bb + (long long)(n0+lrow)*sB + lcol;
  u16* lAw = lA + wave*512;   // HW writes lds_base + lane*16B -> element 8*t
  u16* lBw = lB + wave*512;

  f32x4 acc[4][4];
#pragma unroll
  for(int i=0;i<4;i++)
#pragma unroll
    for(int j=0;j<4;j++) acc[i][j] = (f32x4)(0.0f);

  const int l16 = lane & 15, lk8 = (lane>>4)*8;

  for(int kk=0; kk<K; kk+=32){
    GLD16(aSrc,                    lAw);
    GLD16(aSrc + (long long)64*sA, lAw + 64*32);
    GLD16(bSrc,                    lBw);
    GLD16(bSrc + (long long)64*sB, lBw + 64*32);
    aSrc += 32; bSrc += 32;
    __syncthreads();
    bf16x8 af[4], bfr[4];
#pragma unroll
    for(int i=0;i<4;i++){
      af[i]  = *(const bf16x8*)(lA + (wm + i*16 + l16)*32 + lk8);
      bfr[i] = *(const bf16x8*)(lB + (wn + i*16 + l16)*32 + lk8);
    }
#pragma unroll
    for(int i=0;i<4;i++)
#pragma unroll
      for(int j=0;j<4;j++)
        acc[i][j] = __builtin_amdgcn_mfma_f32_16x16x32_bf16(af[i], bfr[j], acc[i][j], 0,0,0);
    __syncthreads();
  }

  const float dsc = scalePtr ? scalePtr[z] : 1.0f;
  const long long cBase = (long long)zq*zC1 + (long long)zr*zC2;
  const int rbase = (lane>>4)*4;
#pragma unroll
  for(int i=0;i<4;i++){
#pragma unroll
    for(int j=0;j<4;j++){
#pragma unroll
      for(int r=0;r<4;r++){
        const int row = m0 + wm + i*16 + rbase + r;
        const int col = n0 + wn + j*16 + l16;
        if(row < M){
          float v = acc[i][j][r];
          if(bias1) v += bias1[col];
          v *= hscale * dsc;
          if(bias2) v += bias2[(row/rowsPerB)*b2s + col];
          if(OUT_F32) ((float*)Cm)[cBase + (long long)row*sC + col] = v;
          else        ((u16*) Cm)[cBase + (long long)row*sC + col] = f2b(v);
        }
      }
    }
  }
}

// f32 (K,N) weight -> bf16 (N,K) transpose
__global__ __launch_bounds__(256)
void wt_kernel(const float* __restrict__ W, u16* __restrict__ Wt, int K, int N){
  __shared__ float tile[32][33];
  const int n0 = blockIdx.x*32, k0 = blockIdx.y*32;
  const int t = threadIdx.x, tr = t>>5, tc = t&31;
#pragma unroll
  for(int i=0;i<4;i++)
    tile[tr+i*8][tc] = W[(long long)(k0+tr+i*8)*N + n0+tc];
  __syncthreads();
#pragma unroll
  for(int i=0;i<4;i++)
    Wt[(long long)(n0+tr+i*8)*K + k0+tc] = f2b(tile[tc][tr+i*8]);
}

__global__ __launch_bounds__(256)
void cvt_bf16(const float* __restrict__ in, u16* __restrict__ outp, long long n){
  long long i = ((long long)blockIdx.x*256 + threadIdx.x)*4;
  if(i+3 < n){
    float4 v = *(const float4*)(in+i);
    ushort4 o; o.x=f2b(v.x); o.y=f2b(v.y); o.z=f2b(v.z); o.w=f2b(v.w);
    *(ushort4*)(outp+i) = o;
  }
}

// depthwise 3x3 stride-2 SAME conv (pad lo=0,hi=1) + bias + LayerNorm -> bf16
__global__ __launch_bounds__(256)
void conv_ln(const float* __restrict__ q, const float* __restrict__ ker,
             const float* __restrict__ cbias, const float* __restrict__ gamma,
             const float* __restrict__ beta, u16* __restrict__ xo)
{
  const int p = blockIdx.x;            // b*784 + pix
  const int b = p / 784, pix = p % 784;
  const int oy = pix / 28, ox = pix % 28;
  const int t = threadIdx.x;
  __shared__ float red[256];
  float v[2];
#pragma unroll
  for(int e=0;e<2;e++){
    const int c = t + e*256;
    float acc = cbias[c];
    for(int ky=0;ky<3;ky++){
      const int y = oy*2 + ky;
      if(y >= HIMG) continue;
      for(int kx=0;kx<3;kx++){
        const int x = ox*2 + kx;
        if(x >= WIMG) continue;
        acc += q[(((long long)b*HIMG + y)*WIMG + x)*C_ + c] * ker[(ky*3+kx)*C_ + c];
      }
    }
    v[e] = acc;
  }
  red[t]=v[0]+v[1]; __syncthreads();
  for(int st=128; st>0; st>>=1){ if(t<st) red[t]+=red[t+st]; __syncthreads(); }
  const float mu = red[0] * (1.0f/C_);
  __syncthreads();
  const float d0=v[0]-mu, d1=v[1]-mu;
  red[t]=d0*d0+d1*d1; __syncthreads();
  for(int st=128; st>0; st>>=1){ if(t<st) red[t]+=red[t+st]; __syncthreads(); }
  const float rs = rsqrtf(red[0]*(1.0f/C_) + 1e-3f);
  const long long ob = (long long)p*C_;
#pragma unroll
  for(int e=0;e<2;e++){
    const int c = t+e*256;
    xo[ob+c] = f2b((v[e]-mu)*rs*gamma[c] + beta[c]);
  }
}

// per-batch: Vf_b (784,4096) -> Vt_b (4096,896) transposed, k zero-padded
__global__ __launch_bounds__(256)
void vt_kernel(const u16* __restrict__ Vf_b, u16* __restrict__ Vt_b){
  __shared__ u16 tile[32][33];
  const int k0 = blockIdx.x*32, d0 = blockIdx.y*32;
  const int t = threadIdx.x, tr = t>>5, tc = t&31;
#pragma unroll
  for(int i=0;i<4;i++){
    const int k = k0+tr+i*8;
    tile[tr+i*8][tc] = (k < NK_) ? Vf_b[(long long)k*HD_ + d0+tc] : (u16)0;
  }
  __syncthreads();
#pragma unroll
  for(int i=0;i<4;i++)
    Vt_b[(long long)(d0+tr+i*8)*NKP_ + k0+tc] = tile[tc][tr+i*8];
}

// per-batch: scores S_b[h,q,0..783] bf16; mix over h with tw, softmax over k,
// write deviations p - 1/784 back at [g,q,:], zero cols 784..895,
// accumulate sum(dev^2) per g. tb cancels in softmax exactly.
__global__ __launch_bounds__(256)
void mix_softmax(u16* __restrict__ S_b, const float* __restrict__ tw,
                 float* __restrict__ sumsq_b)
{
  const int qi = blockIdx.x;
  const int t = threadIdx.x;
  __shared__ float sv[8][NK_];
  __shared__ float tg[NK_];
  __shared__ float red[256];
  const long long rowstr = (long long)NQ_*NKP_;
  const long long base = (long long)qi*NKP_;
  for(int h=0; h<8; h++){
    const u16* src = S_b + base + h*rowstr;
    for(int k=t; k<NK_; k+=256) sv[h][k] = b2f(src[k]);
  }
  __syncthreads();
  for(int g=0; g<8; g++){
    float w[8];
#pragma unroll
    for(int h=0;h<8;h++) w[h] = tw[h*8+g];
    float lmax = -1e30f;
    for(int k=t; k<NK_; k+=256){
      float x = 0.f;
#pragma unroll
      for(int h=0;h<8;h++) x += w[h]*sv[h][k];
      tg[k] = x;
      lmax = fmaxf(lmax, x);
    }
    red[t]=lmax; __syncthreads();
    for(int st=128; st>0; st>>=1){ if(t<st) red[t]=fmaxf(red[t],red[t+st]); __syncthreads(); }
    const float mx = red[0]; __syncthreads();
    float lsum=0.f;
    for(int k=t; k<NK_; k+=256){
      float e = __expf(tg[k]-mx);
      tg[k]=e; lsum+=e;
    }
    red[t]=lsum; __syncthreads();
    for(int st=128; st>0; st>>=1){ if(t<st) red[t]+=red[t+st]; __syncthreads(); }
    const float inv = 1.0f/red[0]; __syncthreads();
    u16* dst = S_b + base + g*rowstr;
    float lss=0.f;
    for(int k=t; k<NK_; k+=256){
      const float dev = tg[k]*inv - (1.0f/NK_);
      dst[k] = f2b(dev);
      lss += dev*dev;
    }
    for(int k=NK_+t; k<NKP_; k+=256) dst[k]=0;
    red[t]=lss; __syncthreads();
    for(int st=128; st>0; st>>=1){ if(t<st) red[t]+=red[t+st]; __syncthreads(); }
    if(t==0) atomicAdd(&sumsq_b[g], red[0]);
    __syncthreads();
  }
}

__global__ __launch_bounds__(256)
void colsum_v(const u16* __restrict__ Vf_b, float* __restrict__ cs_b){
  const int hd = blockIdx.x*256 + threadIdx.x;
  const u16* p = Vf_b + hd;
  float s=0.f;
  for(int k=0;k<NK_;k++) s += b2f(p[(long long)k*HD_]);
  cs_b[hd]=s;
}

__global__
void finalize_stats(const float* __restrict__ sumsq_b, const float* __restrict__ bng_b,
                    const float* __restrict__ bnb_b, float* __restrict__ a_b,
                    float* __restrict__ c_b){
  const int g = threadIdx.x;
  if(g<8){
    const float s2 = sumsq_b[g] * (1.0f/((float)NQ_*(float)NK_)); // m = 1/784 exact
    a_b[g] = bng_b[g]*rsqrtf(s2 + 1e-3f);
    c_b[g] = bnb_b[g];
  }
}

// corr_b[n] = sum_g c_b[g] * (colsumV_b[g*512:(g+1)*512] . Wo_g[:,n])
__global__ __launch_bounds__(256)
void corr_kernel(const float* __restrict__ cs_b, const u16* __restrict__ Wot,
                 const float* __restrict__ c_b, float* __restrict__ corr_b){
  const int n = blockIdx.x, t = threadIdx.x;
  __shared__ float red[256];
  float s = 0.f;
  for(int hd=t; hd<HD_; hd+=256)
    s += c_b[hd>>9] * cs_b[hd] * b2f(Wot[(long long)n*HD_+hd]);
  red[t]=s; __syncthreads();
  for(int st=128; st>0; st>>=1){ if(t<st) red[t]+=red[t+st]; __syncthreads(); }
  if(t==0) corr_b[n]=red[0];
}

// ---------------------------------------------------------------------------
extern "C" void kernel_launch(void* const* d_in, const int* in_sizes, int n_in,
                              void* d_out, int out_size, void* d_ws, size_t ws_size,
                              hipStream_t stream)
{
  (void)in_sizes; (void)n_in; (void)out_size;
  const float* queries = (const float*)d_in[0];
  const float* Wq  = (const float*)d_in[3];
  const float* bq  = (const float*)d_in[4];
  const float* Wk  = (const float*)d_in[5];
  const float* bk  = (const float*)d_in[6];
  const float* Wv  = (const float*)d_in[7];
  const float* bv  = (const float*)d_in[8];
  const float* Wo  = (const float*)d_in[9];
  const float* bo  = (const float*)d_in[10];
  const float* srk = (const float*)d_in[11];
  const float* srb = (const float*)d_in[12];
  const float* lng = (const float*)d_in[13];
  const float* lnb = (const float*)d_in[14];
  const float* tw  = (const float*)d_in[15];
  // d_in[16] tb: constant over k -> cancels in softmax (exact)
  const float* bng = (const float*)d_in[17];
  const float* bnb = (const float*)d_in[18];
  float* out = (float*)d_out;
  const float QSC = 0.04419417382415922f;   // 1/sqrt(512)

  char* w = (char*)d_ws;
  size_t off = 0;
  auto alloc = [&](size_t bytes)->char*{
    char* p = w + off; off += (bytes + 255) & ~(size_t)255; return p;
  };

  // Tier select: A needs ~202 MB, B needs ~110 MB.
  const bool tierA = (ws_size >= (size_t)210*1024*1024);

  u16* Wqt = (u16*)alloc((size_t)HD_*C_*2);
  u16* Wkt = (u16*)alloc((size_t)HD_*C_*2);
  u16* Wvt = (u16*)alloc((size_t)HD_*C_*2);
  u16* Wot = (u16*)alloc((size_t)C_*HD_*2);
  u16* x   = (u16*)alloc((size_t)B_*NK_*C_*2 + 131072);     // +128K over-read pad
  u16* Qin;       // tier A: full (12544,512); tier B: per-b (3136,512)
  u16* QfU;       // tier A: full (12544,4096); tier B: per-b (3136,4096)
  if(tierA){
    Qin = (u16*)alloc((size_t)B_*NQ_*C_*2);
    QfU = (u16*)alloc((size_t)B_*NQ_*HD_*2);
  } else {
    Qin = (u16*)alloc((size_t)NQ_*C_*2 + 131072);
    QfU = (u16*)alloc((size_t)NQ_*HD_*2);
  }
  u16* Kf_b = (u16*)alloc((size_t)NK_*HD_*2);   // score B-side over-reads into Vf_b
  u16* Vf_b = (u16*)alloc((size_t)NK_*HD_*2);
  u16* Vt_b = (u16*)alloc((size_t)HD_*NKP_*2);
  u16* S_b  = (u16*)alloc((size_t)8*NQ_*NKP_*2 + 262144);   // +256K over-read pad
  float* colsum = (float*)alloc((size_t)B_*HD_*4);
  float* sumsq  = (float*)alloc(256);
  float* aArr   = (float*)alloc(256);
  float* cArr   = (float*)alloc(256);
  float* corrB  = (float*)alloc((size_t)B_*C_*4);

  // ---- weight prep + conv+LN (batch-independent) ----
  wt_kernel<<<dim3(128,16), 256, 0, stream>>>(Wq, Wqt, 512, 4096);
  wt_kernel<<<dim3(128,16), 256, 0, stream>>>(Wk, Wkt, 512, 4096);
  wt_kernel<<<dim3(128,16), 256, 0, stream>>>(Wv, Wvt, 512, 4096);
  wt_kernel<<<dim3(16,128), 256, 0, stream>>>(Wo, Wot, 4096, 512);
  conv_ln<<<B_*NK_, 256, 0, stream>>>(queries, srk, srb, lng, lnb, x);
  hipMemsetAsync(sumsq, 0, 32*sizeof(float), stream);

  if(tierA){
    cvt_bf16<<<6272, 256, 0, stream>>>(queries, Qin, (long long)B_*NQ_*C_);
    // Qf = (queries@Wq + bq)/sqrt(512), full batch
    gemm_bt<0><<<dim3(98,32,1),256,0,stream>>>(Qin, Wqt, QfU, B_*NQ_, 512, 512, 512, HD_,
        1, 0,0,0,0,0,0, bq, QSC, nullptr, nullptr, 1, 0);
  }

  for(int b=0; b<B_; b++){
    u16* Qf_b = tierA ? (QfU + (size_t)b*NQ_*HD_) : QfU;
    if(!tierA){
      cvt_bf16<<<1568, 256, 0, stream>>>(queries + (size_t)b*NQ_*C_, Qin, (long long)NQ_*C_);
      gemm_bt<0><<<dim3(25,32,1),256,0,stream>>>(Qin, Wqt, Qf_b, NQ_, 512, 512, 512, HD_,
          1, 0,0,0,0,0,0, bq, QSC, nullptr, nullptr, 1, 0);
    }
    // K/V projections from LN'd conv output rows of batch b
    const u16* x_b = x + (size_t)b*NK_*C_;
    gemm_bt<0><<<dim3(7,32,1),256,0,stream>>>(x_b, Wkt, Kf_b, NK_, 512, 512, 512, HD_,
        1, 0,0,0,0,0,0, bk, 1.0f, nullptr, nullptr, 1, 0);
    gemm_bt<0><<<dim3(7,32,1),256,0,stream>>>(x_b, Wvt, Vf_b, NK_, 512, 512, 512, HD_,
        1, 0,0,0,0,0,0, bv, 1.0f, nullptr, nullptr, 1, 0);
    vt_kernel<<<dim3(28,128),256,0,stream>>>(Vf_b, Vt_b);
    colsum_v<<<16,256,0,stream>>>(Vf_b, colsum + b*HD_);
    // per-head scores: S_b[h] = Qf_b[:, h*512:+512] @ Kf_b[:, h*512:+512]^T
    gemm_bt<0><<<dim3(25,7,8),256,0,stream>>>(Qf_b, Kf_b, S_b, NQ_, 512, HD_, HD_, NKP_,
        8, 0, 512, 0, 512, 0, (long long)NQ_*NKP_,
        nullptr, 1.0f, nullptr, nullptr, 1, 0);
    mix_softmax<<<NQ_, 256, 0, stream>>>(S_b, tw, sumsq + b*8);
    finalize_stats<<<1,64,0,stream>>>(sumsq + b*8, bng + b*8, bnb + b*8, aArr + b*8, cArr + b*8);
    corr_kernel<<<512,256,0,stream>>>(colsum + b*HD_, Wot, cArr + b*8, corrB + b*C_);
    // U_b[:, g*512+d] = a[b,g] * (P~_g @ V_g)   (overwrites Qf_b; safe: Qf_b dead)
    gemm_bt<0><<<dim3(25,4,8),256,0,stream>>>(S_b, Vt_b, Qf_b, NQ_, NKP_, NKP_, NKP_, HD_,
        8, 0, (long long)NQ_*NKP_, 0, (long long)512*NKP_, 0, 512,
        nullptr, 1.0f, aArr + b*8, nullptr, 1, 0);
    if(!tierA){
      gemm_bt<1><<<dim3(25,4,1),256,0,stream>>>(Qf_b, Wot, out + (size_t)b*NQ_*C_,
          NQ_, HD_, HD_, HD_, C_,
          1, 0,0,0,0,0,0, bo, 1.0f, nullptr, corrB + b*C_, NQ_, C_);
    }
  }

  if(tierA){
    // out = U @ Wo + bo + corr[b,:]
    gemm_bt<1><<<dim3(98,4,1),256,0,stream>>>(QfU, Wot, out, B_*NQ_, HD_, HD_, HD_, C_,
        1, 0,0,0,0,0,0, bo, 1.0f, nullptr, corrB, NQ_, C_);
  }
}

// Round 3
// 2480.701 us; speedup vs baseline: 1.0326x; 1.0326x over previous
//
#include <hip/hip_runtime.h>
#include <hip/hip_bf16.h>
#include <math.h>

typedef unsigned short u16;
typedef __attribute__((ext_vector_type(4))) float f32x4;
typedef __attribute__((ext_vector_type(8))) __bf16 bf16x8;

#define B_    4
#define NQ_   3136
#define C_    512
#define HIMG  56
#define WIMG  56
#define HD_   4096
#define NK_   784
#define NKP_  896

static __device__ __forceinline__ float b2f(u16 u){
  union { unsigned int i; float f; } v; v.i = ((unsigned int)u)<<16; return v.f;
}
static __device__ __forceinline__ u16 f2b(float f){
  union { float f; unsigned int i; } v; v.f = f;
  unsigned int r = v.i + 0x7fffu + ((v.i>>16)&1u);
  return (u16)(r>>16);
}

#define GLD16(gsrc, ldst) __builtin_amdgcn_global_load_lds( \
    (const __attribute__((address_space(1))) void*)(gsrc), \
    (__attribute__((address_space(3))) void*)(ldst), 16, 0, 0)

// ---------------------------------------------------------------------------
// bf16 GEMM: C[m,n] = (sum_k A[m,k]*B[n,k] + bias1[n]) * hscale * dsc + bias2
// A: (M,K) bf16 row-major stride sA; B: (N,K) bf16 row-major stride sB.
// 128x128 tile, BK=32, 4 waves of 64x64, mfma 16x16x32, global_load_lds w=16.
// A/B loads are NOT masked in M/N (caller guarantees in-ws over-read slack);
// stores masked by row<M only (cols always valid by construction).
// ---------------------------------------------------------------------------
template<int OUT_F32>
__global__ __launch_bounds__(256)
void gemm_bt(const u16* __restrict__ A, const u16* __restrict__ Bm, void* __restrict__ Cm,
             int M, int K, int sA, int sB, int sC, int zdiv,
             long long zA1, long long zA2, long long zB1, long long zB2,
             long long zC1, long long zC2,
             const float* __restrict__ bias1, float hscale,
             const float* __restrict__ scalePtr,
             const float* __restrict__ bias2, int rowsPerB, int b2s)
{
  __shared__ u16 lA[128*32];
  __shared__ u16 lB[128*32];
  const int z  = blockIdx.z;
  const int zq = z / zdiv, zr = z % zdiv;
  const u16* Ab = A  + (long long)zq*zA1 + (long long)zr*zA2;
  const u16* Bb = Bm + (long long)zq*zB1 + (long long)zr*zB2;
  const int m0 = blockIdx.x*128, n0 = blockIdx.y*128;
  const int t = threadIdx.x, wave = t>>6, lane = t&63;
  const int wm = (wave>>1)*64, wn = (wave&1)*64;
  const int lrow = t>>2, lcol = (t&3)*8;

  const u16* aSrc = Ab + (long long)(m0+lrow)*sA + lcol;
  const u16* bSrc = Bb + (long long)(n0+lrow)*sB + lcol;
  u16* lAw = lA + wave*512;   // HW writes lds_base + lane*16B -> element 8*t
  u16* lBw = lB + wave*512;

  f32x4 acc[4][4];
#pragma unroll
  for(int i=0;i<4;i++)
#pragma unroll
    for(int j=0;j<4;j++) acc[i][j] = (f32x4)(0.0f);

  const int l16 = lane & 15, lk8 = (lane>>4)*8;

  for(int kk=0; kk<K; kk+=32){
    GLD16(aSrc,                    lAw);
    GLD16(aSrc + (long long)64*sA, lAw + 64*32);
    GLD16(bSrc,                    lBw);
    GLD16(bSrc + (long long)64*sB, lBw + 64*32);
    aSrc += 32; bSrc += 32;
    __syncthreads();
    bf16x8 af[4], bfr[4];
#pragma unroll
    for(int i=0;i<4;i++){
      af[i]  = *(const bf16x8*)(lA + (wm + i*16 + l16)*32 + lk8);
      bfr[i] = *(const bf16x8*)(lB + (wn + i*16 + l16)*32 + lk8);
    }
#pragma unroll
    for(int i=0;i<4;i++)
#pragma unroll
      for(int j=0;j<4;j++)
        acc[i][j] = __builtin_amdgcn_mfma_f32_16x16x32_bf16(af[i], bfr[j], acc[i][j], 0,0,0);
    __syncthreads();
  }

  const float dsc = scalePtr ? scalePtr[z] : 1.0f;
  const long long cBase = (long long)zq*zC1 + (long long)zr*zC2;
  const int rbase = (lane>>4)*4;
#pragma unroll
  for(int i=0;i<4;i++){
#pragma unroll
    for(int j=0;j<4;j++){
#pragma unroll
      for(int r=0;r<4;r++){
        const int row = m0 + wm + i*16 + rbase + r;
        const int col = n0 + wn + j*16 + l16;
        if(row < M){
          float v = acc[i][j][r];
          if(bias1) v += bias1[col];
          v *= hscale * dsc;
          if(bias2) v += bias2[(row/rowsPerB)*b2s + col];
          if(OUT_F32) ((float*)Cm)[cBase + (long long)row*sC + col] = v;
          else        ((u16*) Cm)[cBase + (long long)row*sC + col] = f2b(v);
        }
      }
    }
  }
}

// f32 (K,N) weight -> bf16 (N,K) transpose
__global__ __launch_bounds__(256)
void wt_kernel(const float* __restrict__ W, u16* __restrict__ Wt, int K, int N){
  __shared__ float tile[32][33];
  const int n0 = blockIdx.x*32, k0 = blockIdx.y*32;
  const int t = threadIdx.x, tr = t>>5, tc = t&31;
#pragma unroll
  for(int i=0;i<4;i++)
    tile[tr+i*8][tc] = W[(long long)(k0+tr+i*8)*N + n0+tc];
  __syncthreads();
#pragma unroll
  for(int i=0;i<4;i++)
    Wt[(long long)(n0+tr+i*8)*K + k0+tc] = f2b(tile[tc][tr+i*8]);
}

__global__ __launch_bounds__(256)
void cvt_bf16(const float* __restrict__ in, u16* __restrict__ outp, long long n){
  long long i = ((long long)blockIdx.x*256 + threadIdx.x)*4;
  if(i+3 < n){
    float4 v = *(const float4*)(in+i);
    ushort4 o; o.x=f2b(v.x); o.y=f2b(v.y); o.z=f2b(v.z); o.w=f2b(v.w);
    *(ushort4*)(outp+i) = o;
  }
}

// depthwise 3x3 stride-2 SAME conv (pad lo=0,hi=1) + bias + LayerNorm -> bf16
__global__ __launch_bounds__(256)
void conv_ln(const float* __restrict__ q, const float* __restrict__ ker,
             const float* __restrict__ cbias, const float* __restrict__ gamma,
             const float* __restrict__ beta, u16* __restrict__ xo)
{
  const int p = blockIdx.x;            // b*784 + pix
  const int b = p / 784, pix = p % 784;
  const int oy = pix / 28, ox = pix % 28;
  const int t = threadIdx.x;
  __shared__ float red[256];
  float v[2];
#pragma unroll
  for(int e=0;e<2;e++){
    const int c = t + e*256;
    float acc = cbias[c];
    for(int ky=0;ky<3;ky++){
      const int y = oy*2 + ky;
      if(y >= HIMG) continue;
      for(int kx=0;kx<3;kx++){
        const int x = ox*2 + kx;
        if(x >= WIMG) continue;
        acc += q[(((long long)b*HIMG + y)*WIMG + x)*C_ + c] * ker[(ky*3+kx)*C_ + c];
      }
    }
    v[e] = acc;
  }
  red[t]=v[0]+v[1]; __syncthreads();
  for(int st=128; st>0; st>>=1){ if(t<st) red[t]+=red[t+st]; __syncthreads(); }
  const float mu = red[0] * (1.0f/C_);
  __syncthreads();
  const float d0=v[0]-mu, d1=v[1]-mu;
  red[t]=d0*d0+d1*d1; __syncthreads();
  for(int st=128; st>0; st>>=1){ if(t<st) red[t]+=red[t+st]; __syncthreads(); }
  const float rs = rsqrtf(red[0]*(1.0f/C_) + 1e-3f);
  const long long ob = (long long)p*C_;
#pragma unroll
  for(int e=0;e<2;e++){
    const int c = t+e*256;
    xo[ob+c] = f2b((v[e]-mu)*rs*gamma[c] + beta[c]);
  }
}

// per-batch: Vf_b (784,4096) -> Vt_b (4096,896) transposed, k zero-padded
__global__ __launch_bounds__(256)
void vt_kernel(const u16* __restrict__ Vf_b, u16* __restrict__ Vt_b){
  __shared__ u16 tile[32][33];
  const int k0 = blockIdx.x*32, d0 = blockIdx.y*32;
  const int t = threadIdx.x, tr = t>>5, tc = t&31;
#pragma unroll
  for(int i=0;i<4;i++){
    const int k = k0+tr+i*8;
    tile[tr+i*8][tc] = (k < NK_) ? Vf_b[(long long)k*HD_ + d0+tc] : (u16)0;
  }
  __syncthreads();
#pragma unroll
  for(int i=0;i<4;i++)
    Vt_b[(long long)(d0+tr+i*8)*NKP_ + k0+tc] = tile[tc][tr+i*8];
}

// ---------------------------------------------------------------------------
// Wave-parallel mix+softmax: one block (512 thr = 8 waves) per q-row.
// Stage S_b[h,q,0..783] (8 heads) into LDS once; wave g computes head-mix,
// softmax over k, writes deviations p - 1/784 bf16 to [g,q,:], zeros the
// 784..895 pad, and atomically accumulates sum(dev^2) into sumsq_b[g].
// All reductions are barrier-free 64-lane shfl_xor butterflies.
// tb cancels in softmax exactly (constant over k).
// ---------------------------------------------------------------------------
__global__ __launch_bounds__(512)
void mix_softmax(u16* __restrict__ S_b, const float* __restrict__ tw,
                 float* __restrict__ sumsq_b)
{
  const int qi = blockIdx.x;
  const int t = threadIdx.x;
  const int wave = t >> 6, lane = t & 63;
  __shared__ float sv[8*NK_];
  const long long rowstr = (long long)NQ_*NKP_;
  const long long base = (long long)qi*NKP_;

  // stage: 8 rows x 784 bf16 -> f32 LDS, vectorized ushort4 (196 per row)
  for(int idx = t; idx < 8*196; idx += 512){
    const int h = idx / 196, c4 = idx % 196;
    ushort4 u4 = *(const ushort4*)(S_b + base + h*rowstr + c4*4);
    float* d = sv + h*NK_ + c4*4;
    d[0]=b2f(u4.x); d[1]=b2f(u4.y); d[2]=b2f(u4.z); d[3]=b2f(u4.w);
  }
  __syncthreads();

  const int g = wave;
  float wgt[8];
#pragma unroll
  for(int h=0;h<8;h++) wgt[h] = tw[h*8+g];

  float xs[13];
  float lmax = -1e30f;
#pragma unroll
  for(int j=0;j<13;j++){
    const int k = j*64 + lane;
    if(k < NK_){
      float x = 0.f;
#pragma unroll
      for(int h=0;h<8;h++) x += wgt[h]*sv[h*NK_+k];
      xs[j] = x;
      lmax = fmaxf(lmax, x);
    } else xs[j] = -1e30f;
  }
#pragma unroll
  for(int off=32; off>=1; off>>=1) lmax = fmaxf(lmax, __shfl_xor(lmax, off));

  float lsum = 0.f;
#pragma unroll
  for(int j=0;j<13;j++){
    const int k = j*64 + lane;
    if(k < NK_){
      const float e = __expf(xs[j] - lmax);
      xs[j] = e; lsum += e;
    }
  }
#pragma unroll
  for(int off=32; off>=1; off>>=1) lsum += __shfl_xor(lsum, off);
  const float inv = 1.0f/lsum;

  u16* dst = S_b + base + g*rowstr;
  float lss = 0.f;
#pragma unroll
  for(int j=0;j<13;j++){
    const int k = j*64 + lane;
    if(k < NK_){
      const float dev = xs[j]*inv - (1.0f/NK_);
      dst[k] = f2b(dev);
      lss += dev*dev;
    }
  }
  for(int k = NK_ + lane; k < NKP_; k += 64) dst[k] = 0;
#pragma unroll
  for(int off=32; off>=1; off>>=1) lss += __shfl_xor(lss, off);
  if(lane==0) atomicAdd(&sumsq_b[g], lss);
}

__global__ __launch_bounds__(256)
void colsum_v(const u16* __restrict__ Vf_b, float* __restrict__ cs_b){
  const int hd = blockIdx.x*256 + threadIdx.x;
  const u16* p = Vf_b + hd;
  float s=0.f;
  for(int k=0;k<NK_;k++) s += b2f(p[(long long)k*HD_]);
  cs_b[hd]=s;
}

__global__
void finalize_stats(const float* __restrict__ sumsq_b, const float* __restrict__ bng_b,
                    const float* __restrict__ bnb_b, float* __restrict__ a_b,
                    float* __restrict__ c_b){
  const int g = threadIdx.x;
  if(g<8){
    const float s2 = sumsq_b[g] * (1.0f/((float)NQ_*(float)NK_)); // m = 1/784 exact
    a_b[g] = bng_b[g]*rsqrtf(s2 + 1e-3f);
    c_b[g] = bnb_b[g];
  }
}

// corr_b[n] = sum_g c_b[g] * (colsumV_b[g*512:(g+1)*512] . Wo_g[:,n])
__global__ __launch_bounds__(256)
void corr_kernel(const float* __restrict__ cs_b, const u16* __restrict__ Wot,
                 const float* __restrict__ c_b, float* __restrict__ corr_b){
  const int n = blockIdx.x, t = threadIdx.x;
  __shared__ float red[256];
  float s = 0.f;
  for(int hd=t; hd<HD_; hd+=256)
    s += c_b[hd>>9] * cs_b[hd] * b2f(Wot[(long long)n*HD_+hd]);
  red[t]=s; __syncthreads();
  for(int st=128; st>0; st>>=1){ if(t<st) red[t]+=red[t+st]; __syncthreads(); }
  if(t==0) corr_b[n]=red[0];
}

// ---------------------------------------------------------------------------
extern "C" void kernel_launch(void* const* d_in, const int* in_sizes, int n_in,
                              void* d_out, int out_size, void* d_ws, size_t ws_size,
                              hipStream_t stream)
{
  (void)in_sizes; (void)n_in; (void)out_size;
  const float* queries = (const float*)d_in[0];
  const float* Wq  = (const float*)d_in[3];
  const float* bq  = (const float*)d_in[4];
  const float* Wk  = (const float*)d_in[5];
  const float* bk  = (const float*)d_in[6];
  const float* Wv  = (const float*)d_in[7];
  const float* bv  = (const float*)d_in[8];
  const float* Wo  = (const float*)d_in[9];
  const float* bo  = (const float*)d_in[10];
  const float* srk = (const float*)d_in[11];
  const float* srb = (const float*)d_in[12];
  const float* lng = (const float*)d_in[13];
  const float* lnb = (const float*)d_in[14];
  const float* tw  = (const float*)d_in[15];
  // d_in[16] tb: constant over k -> cancels in softmax (exact)
  const float* bng = (const float*)d_in[17];
  const float* bnb = (const float*)d_in[18];
  float* out = (float*)d_out;
  const float QSC = 0.04419417382415922f;   // 1/sqrt(512)

  char* w = (char*)d_ws;
  size_t off = 0;
  auto alloc = [&](size_t bytes)->char*{
    char* p = w + off; off += (bytes + 255) & ~(size_t)255; return p;
  };

  // Tier select: A needs ~202 MB, B needs ~110 MB.
  const bool tierA = (ws_size >= (size_t)210*1024*1024);

  u16* Wqt = (u16*)alloc((size_t)HD_*C_*2);
  u16* Wkt = (u16*)alloc((size_t)HD_*C_*2);
  u16* Wvt = (u16*)alloc((size_t)HD_*C_*2);
  u16* Wot = (u16*)alloc((size_t)C_*HD_*2);
  u16* x   = (u16*)alloc((size_t)B_*NK_*C_*2 + 131072);     // +128K over-read pad
  u16* Qin;       // tier A: full (12544,512); tier B: per-b (3136,512)
  u16* QfU;       // tier A: full (12544,4096); tier B: per-b (3136,4096)
  if(tierA){
    Qin = (u16*)alloc((size_t)B_*NQ_*C_*2);
    QfU = (u16*)alloc((size_t)B_*NQ_*HD_*2);
  } else {
    Qin = (u16*)alloc((size_t)NQ_*C_*2 + 131072);
    QfU = (u16*)alloc((size_t)NQ_*HD_*2);
  }
  u16* Kf_b = (u16*)alloc((size_t)NK_*HD_*2);   // score B-side over-reads into Vf_b
  u16* Vf_b = (u16*)alloc((size_t)NK_*HD_*2);
  u16* Vt_b = (u16*)alloc((size_t)HD_*NKP_*2);
  u16* S_b  = (u16*)alloc((size_t)8*NQ_*NKP_*2 + 262144);   // +256K over-read pad
  float* colsum = (float*)alloc((size_t)B_*HD_*4);
  float* sumsq  = (float*)alloc(256);
  float* aArr   = (float*)alloc(256);
  float* cArr   = (float*)alloc(256);
  float* corrB  = (float*)alloc((size_t)B_*C_*4);

  // ---- weight prep + conv+LN (batch-independent) ----
  wt_kernel<<<dim3(128,16), 256, 0, stream>>>(Wq, Wqt, 512, 4096);
  wt_kernel<<<dim3(128,16), 256, 0, stream>>>(Wk, Wkt, 512, 4096);
  wt_kernel<<<dim3(128,16), 256, 0, stream>>>(Wv, Wvt, 512, 4096);
  wt_kernel<<<dim3(16,128), 256, 0, stream>>>(Wo, Wot, 4096, 512);
  conv_ln<<<B_*NK_, 256, 0, stream>>>(queries, srk, srb, lng, lnb, x);
  hipMemsetAsync(sumsq, 0, 32*sizeof(float), stream);

  if(tierA){
    cvt_bf16<<<6272, 256, 0, stream>>>(queries, Qin, (long long)B_*NQ_*C_);
    // Qf = (queries@Wq + bq)/sqrt(512), full batch
    gemm_bt<0><<<dim3(98,32,1),256,0,stream>>>(Qin, Wqt, QfU, B_*NQ_, 512, 512, 512, HD_,
        1, 0,0,0,0,0,0, bq, QSC, nullptr, nullptr, 1, 0);
  }

  for(int b=0; b<B_; b++){
    u16* Qf_b = tierA ? (QfU + (size_t)b*NQ_*HD_) : QfU;
    if(!tierA){
      cvt_bf16<<<1568, 256, 0, stream>>>(queries + (size_t)b*NQ_*C_, Qin, (long long)NQ_*C_);
      gemm_bt<0><<<dim3(25,32,1),256,0,stream>>>(Qin, Wqt, Qf_b, NQ_, 512, 512, 512, HD_,
          1, 0,0,0,0,0,0, bq, QSC, nullptr, nullptr, 1, 0);
    }
    // K/V projections from LN'd conv output rows of batch b
    const u16* x_b = x + (size_t)b*NK_*C_;
    gemm_bt<0><<<dim3(7,32,1),256,0,stream>>>(x_b, Wkt, Kf_b, NK_, 512, 512, 512, HD_,
        1, 0,0,0,0,0,0, bk, 1.0f, nullptr, nullptr, 1, 0);
    gemm_bt<0><<<dim3(7,32,1),256,0,stream>>>(x_b, Wvt, Vf_b, NK_, 512, 512, 512, HD_,
        1, 0,0,0,0,0,0, bv, 1.0f, nullptr, nullptr, 1, 0);
    vt_kernel<<<dim3(28,128),256,0,stream>>>(Vf_b, Vt_b);
    colsum_v<<<16,256,0,stream>>>(Vf_b, colsum + b*HD_);
    // per-head scores: S_b[h] = Qf_b[:, h*512:+512] @ Kf_b[:, h*512:+512]^T
    gemm_bt<0><<<dim3(25,7,8),256,0,stream>>>(Qf_b, Kf_b, S_b, NQ_, 512, HD_, HD_, NKP_,
        8, 0, 512, 0, 512, 0, (long long)NQ_*NKP_,
        nullptr, 1.0f, nullptr, nullptr, 1, 0);
    mix_softmax<<<NQ_, 512, 0, stream>>>(S_b, tw, sumsq + b*8);
    finalize_stats<<<1,64,0,stream>>>(sumsq + b*8, bng + b*8, bnb + b*8, aArr + b*8, cArr + b*8);
    corr_kernel<<<512,256,0,stream>>>(colsum + b*HD_, Wot, cArr + b*8, corrB + b*C_);
    // U_b[:, g*512+d] = a[b,g] * (P~_g @ V_g)   (overwrites Qf_b; safe: Qf_b dead)
    gemm_bt<0><<<dim3(25,4,8),256,0,stream>>>(S_b, Vt_b, Qf_b, NQ_, NKP_, NKP_, NKP_, HD_,
        8, 0, (long long)NQ_*NKP_, 0, (long long)512*NKP_, 0, 512,
        nullptr, 1.0f, aArr + b*8, nullptr, 1, 0);
    if(!tierA){
      gemm_bt<1><<<dim3(25,4,1),256,0,stream>>>(Qf_b, Wot, out + (size_t)b*NQ_*C_,
          NQ_, HD_, HD_, HD_, C_,
          1, 0,0,0,0,0,0, bo, 1.0f, nullptr, corrB + b*C_, NQ_, C_);
    }
  }

  if(tierA){
    // out = U @ Wo + bo + corr[b,:]
    gemm_bt<1><<<dim3(98,4,1),256,0,stream>>>(QfU, Wot, out, B_*NQ_, HD_, HD_, HD_, C_,
        1, 0,0,0,0,0,0, bo, 1.0f, nullptr, corrB, NQ_, C_);
  }
}

// Round 4
// 1271.156 us; speedup vs baseline: 2.0151x; 1.9515x over previous
//
#include <hip/hip_runtime.h>
#include <hip/hip_bf16.h>
#include <math.h>

typedef unsigned short u16;
typedef __attribute__((ext_vector_type(4))) float f32x4;
typedef __attribute__((ext_vector_type(8))) __bf16 bf16x8;

#define B_    4
#define NQ_   3136
#define C_    512
#define HIMG  56
#define WIMG  56
#define HD_   4096
#define NK_   784
#define NKP_  896

static __device__ __forceinline__ float b2f(u16 u){
  union { unsigned int i; float f; } v; v.i = ((unsigned int)u)<<16; return v.f;
}
static __device__ __forceinline__ u16 f2b(float f){
  union { float f; unsigned int i; } v; v.f = f;
  unsigned int r = v.i + 0x7fffu + ((v.i>>16)&1u);
  return (u16)(r>>16);
}

#define GLD16(gsrc, ldst) __builtin_amdgcn_global_load_lds( \
    (const __attribute__((address_space(1))) void*)(gsrc), \
    (__attribute__((address_space(3))) void*)(ldst), 16, 0, 0)

// ---------------------------------------------------------------------------
// bf16 GEMM: C[m,n] = (sum_k A[m,k]*B[n,k] + bias1[n]) * hscale * dsc + bias2
// A: (M,K) bf16 row-major stride sA; B: (N,K) bf16 row-major stride sB.
// 128x128 tile, BK=32, 4 waves of 64x64, mfma 16x16x32, global_load_lds w=16.
// A/B loads are NOT masked in M/N (caller guarantees in-ws over-read slack);
// stores masked by row<M only (cols always valid by construction).
// ---------------------------------------------------------------------------
template<int OUT_F32>
__global__ __launch_bounds__(256)
void gemm_bt(const u16* __restrict__ A, const u16* __restrict__ Bm, void* __restrict__ Cm,
             int M, int K, int sA, int sB, int sC, int zdiv,
             long long zA1, long long zA2, long long zB1, long long zB2,
             long long zC1, long long zC2,
             const float* __restrict__ bias1, float hscale,
             const float* __restrict__ scalePtr,
             const float* __restrict__ bias2, int rowsPerB, int b2s)
{
  __shared__ u16 lA[128*32];
  __shared__ u16 lB[128*32];
  const int z  = blockIdx.z;
  const int zq = z / zdiv, zr = z % zdiv;
  const u16* Ab = A  + (long long)zq*zA1 + (long long)zr*zA2;
  const u16* Bb = Bm + (long long)zq*zB1 + (long long)zr*zB2;
  const int m0 = blockIdx.x*128, n0 = blockIdx.y*128;
  const int t = threadIdx.x, wave = t>>6, lane = t&63;
  const int wm = (wave>>1)*64, wn = (wave&1)*64;
  const int lrow = t>>2, lcol = (t&3)*8;

  const u16* aSrc = Ab + (long long)(m0+lrow)*sA + lcol;
  const u16* bSrc = Bb + (long long)(n0+lrow)*sB + lcol;
  u16* lAw = lA + wave*512;   // HW writes lds_base + lane*16B -> element 8*t
  u16* lBw = lB + wave*512;

  f32x4 acc[4][4];
#pragma unroll
  for(int i=0;i<4;i++)
#pragma unroll
    for(int j=0;j<4;j++) acc[i][j] = (f32x4)(0.0f);

  const int l16 = lane & 15, lk8 = (lane>>4)*8;

  for(int kk=0; kk<K; kk+=32){
    GLD16(aSrc,                    lAw);
    GLD16(aSrc + (long long)64*sA, lAw + 64*32);
    GLD16(bSrc,                    lBw);
    GLD16(bSrc + (long long)64*sB, lBw + 64*32);
    aSrc += 32; bSrc += 32;
    __syncthreads();
    bf16x8 af[4], bfr[4];
#pragma unroll
    for(int i=0;i<4;i++){
      af[i]  = *(const bf16x8*)(lA + (wm + i*16 + l16)*32 + lk8);
      bfr[i] = *(const bf16x8*)(lB + (wn + i*16 + l16)*32 + lk8);
    }
#pragma unroll
    for(int i=0;i<4;i++)
#pragma unroll
      for(int j=0;j<4;j++)
        acc[i][j] = __builtin_amdgcn_mfma_f32_16x16x32_bf16(af[i], bfr[j], acc[i][j], 0,0,0);
    __syncthreads();
  }

  const float dsc = scalePtr ? scalePtr[z] : 1.0f;
  const long long cBase = (long long)zq*zC1 + (long long)zr*zC2;
  const int rbase = (lane>>4)*4;
#pragma unroll
  for(int i=0;i<4;i++){
#pragma unroll
    for(int j=0;j<4;j++){
#pragma unroll
      for(int r=0;r<4;r++){
        const int row = m0 + wm + i*16 + rbase + r;
        const int col = n0 + wn + j*16 + l16;
        if(row < M){
          float v = acc[i][j][r];
          if(bias1) v += bias1[col];
          v *= hscale * dsc;
          if(bias2) v += bias2[(row/rowsPerB)*b2s + col];
          if(OUT_F32) ((float*)Cm)[cBase + (long long)row*sC + col] = v;
          else        ((u16*) Cm)[cBase + (long long)row*sC + col] = f2b(v);
        }
      }
    }
  }
}

// f32 (K,N) weight -> bf16 (N,K) transpose
__global__ __launch_bounds__(256)
void wt_kernel(const float* __restrict__ W, u16* __restrict__ Wt, int K, int N){
  __shared__ float tile[32][33];
  const int n0 = blockIdx.x*32, k0 = blockIdx.y*32;
  const int t = threadIdx.x, tr = t>>5, tc = t&31;
#pragma unroll
  for(int i=0;i<4;i++)
    tile[tr+i*8][tc] = W[(long long)(k0+tr+i*8)*N + n0+tc];
  __syncthreads();
#pragma unroll
  for(int i=0;i<4;i++)
    Wt[(long long)(n0+tr+i*8)*K + k0+tc] = f2b(tile[tc][tr+i*8]);
}

__global__ __launch_bounds__(256)
void cvt_bf16(const float* __restrict__ in, u16* __restrict__ outp, long long n){
  long long i = ((long long)blockIdx.x*256 + threadIdx.x)*4;
  if(i+3 < n){
    float4 v = *(const float4*)(in+i);
    ushort4 o; o.x=f2b(v.x); o.y=f2b(v.y); o.z=f2b(v.z); o.w=f2b(v.w);
    *(ushort4*)(outp+i) = o;
  }
}

// depthwise 3x3 stride-2 SAME conv (pad lo=0,hi=1) + bias + LayerNorm -> bf16
__global__ __launch_bounds__(256)
void conv_ln(const float* __restrict__ q, const float* __restrict__ ker,
             const float* __restrict__ cbias, const float* __restrict__ gamma,
             const float* __restrict__ beta, u16* __restrict__ xo)
{
  const int p = blockIdx.x;            // b*784 + pix
  const int b = p / 784, pix = p % 784;
  const int oy = pix / 28, ox = pix % 28;
  const int t = threadIdx.x;
  __shared__ float red[256];
  float v[2];
#pragma unroll
  for(int e=0;e<2;e++){
    const int c = t + e*256;
    float acc = cbias[c];
    for(int ky=0;ky<3;ky++){
      const int y = oy*2 + ky;
      if(y >= HIMG) continue;
      for(int kx=0;kx<3;kx++){
        const int x = ox*2 + kx;
        if(x >= WIMG) continue;
        acc += q[(((long long)b*HIMG + y)*WIMG + x)*C_ + c] * ker[(ky*3+kx)*C_ + c];
      }
    }
    v[e] = acc;
  }
  red[t]=v[0]+v[1]; __syncthreads();
  for(int st=128; st>0; st>>=1){ if(t<st) red[t]+=red[t+st]; __syncthreads(); }
  const float mu = red[0] * (1.0f/C_);
  __syncthreads();
  const float d0=v[0]-mu, d1=v[1]-mu;
  red[t]=d0*d0+d1*d1; __syncthreads();
  for(int st=128; st>0; st>>=1){ if(t<st) red[t]+=red[t+st]; __syncthreads(); }
  const float rs = rsqrtf(red[0]*(1.0f/C_) + 1e-3f);
  const long long ob = (long long)p*C_;
#pragma unroll
  for(int e=0;e<2;e++){
    const int c = t+e*256;
    xo[ob+c] = f2b((v[e]-mu)*rs*gamma[c] + beta[c]);
  }
}

// per-batch: Vf_b (784,4096) -> Vt_b (4096,896) transposed, k zero-padded
__global__ __launch_bounds__(256)
void vt_kernel(const u16* __restrict__ Vf_b, u16* __restrict__ Vt_b){
  __shared__ u16 tile[32][33];
  const int k0 = blockIdx.x*32, d0 = blockIdx.y*32;
  const int t = threadIdx.x, tr = t>>5, tc = t&31;
#pragma unroll
  for(int i=0;i<4;i++){
    const int k = k0+tr+i*8;
    tile[tr+i*8][tc] = (k < NK_) ? Vf_b[(long long)k*HD_ + d0+tc] : (u16)0;
  }
  __syncthreads();
#pragma unroll
  for(int i=0;i<4;i++)
    Vt_b[(long long)(d0+tr+i*8)*NKP_ + k0+tc] = tile[tc][tr+i*8];
}

// ---------------------------------------------------------------------------
// Wave-parallel mix+softmax: one block (512 thr = 8 waves) per q-row.
// Stage S_b[h,q,0..783] into LDS once; wave g computes head-mix, softmax,
// writes deviations p - 1/784 bf16 to [g,q,:], zeros the 784..895 pad, and
// STORES its sum(dev^2) to a unique slot partial_b[g*NQ_+qi]  (NO atomics:
// 25088 same-line atomicAdds serialized at L2 and cost ~320us in r2/r3).
// ---------------------------------------------------------------------------
__global__ __launch_bounds__(512)
void mix_softmax(u16* __restrict__ S_b, const float* __restrict__ tw,
                 float* __restrict__ partial_b)
{
  const int qi = blockIdx.x;
  const int t = threadIdx.x;
  const int wave = t >> 6, lane = t & 63;
  __shared__ float sv[8*NK_];
  const long long rowstr = (long long)NQ_*NKP_;
  const long long base = (long long)qi*NKP_;

  // stage: 8 rows x 784 bf16 -> f32 LDS, vectorized ushort4 (196 per row)
  for(int idx = t; idx < 8*196; idx += 512){
    const int h = idx / 196, c4 = idx % 196;
    ushort4 u4 = *(const ushort4*)(S_b + base + h*rowstr + c4*4);
    float* d = sv + h*NK_ + c4*4;
    d[0]=b2f(u4.x); d[1]=b2f(u4.y); d[2]=b2f(u4.z); d[3]=b2f(u4.w);
  }
  __syncthreads();

  const int g = wave;
  float wgt[8];
#pragma unroll
  for(int h=0;h<8;h++) wgt[h] = tw[h*8+g];

  float xs[13];
  float lmax = -1e30f;
#pragma unroll
  for(int j=0;j<13;j++){
    const int k = j*64 + lane;
    if(k < NK_){
      float x = 0.f;
#pragma unroll
      for(int h=0;h<8;h++) x += wgt[h]*sv[h*NK_+k];
      xs[j] = x;
      lmax = fmaxf(lmax, x);
    } else xs[j] = -1e30f;
  }
#pragma unroll
  for(int off=32; off>=1; off>>=1) lmax = fmaxf(lmax, __shfl_xor(lmax, off));

  float lsum = 0.f;
#pragma unroll
  for(int j=0;j<13;j++){
    const int k = j*64 + lane;
    if(k < NK_){
      const float e = __expf(xs[j] - lmax);
      xs[j] = e; lsum += e;
    }
  }
#pragma unroll
  for(int off=32; off>=1; off>>=1) lsum += __shfl_xor(lsum, off);
  const float inv = 1.0f/lsum;

  u16* dst = S_b + base + g*rowstr;
  float lss = 0.f;
#pragma unroll
  for(int j=0;j<13;j++){
    const int k = j*64 + lane;
    if(k < NK_){
      const float dev = xs[j]*inv - (1.0f/NK_);
      dst[k] = f2b(dev);
      lss += dev*dev;
    }
  }
  for(int k = NK_ + lane; k < NKP_; k += 64) dst[k] = 0;
#pragma unroll
  for(int off=32; off>=1; off>>=1) lss += __shfl_xor(lss, off);
  if(lane==0) partial_b[g*NQ_ + qi] = lss;
}

__global__ __launch_bounds__(256)
void colsum_v(const u16* __restrict__ Vf_b, float* __restrict__ cs_b){
  const int hd = blockIdx.x*256 + threadIdx.x;
  const u16* p = Vf_b + hd;
  float s=0.f;
  for(int k=0;k<NK_;k++) s += b2f(p[(long long)k*HD_]);
  cs_b[hd]=s;
}

// block g: sum partial_b[g*NQ_+*] -> BN scale a_b[g] / shift c_b[g]
__global__ __launch_bounds__(256)
void finalize_stats(const float* __restrict__ partial_b, const float* __restrict__ bng_b,
                    const float* __restrict__ bnb_b, float* __restrict__ a_b,
                    float* __restrict__ c_b){
  const int g = blockIdx.x;
  const int t = threadIdx.x;
  __shared__ float red[4];
  float s = 0.f;
  for(int i=t; i<NQ_; i+=256) s += partial_b[g*NQ_ + i];
#pragma unroll
  for(int off=32; off>=1; off>>=1) s += __shfl_xor(s, off);
  if((t&63)==0) red[t>>6] = s;
  __syncthreads();
  if(t==0){
    const float tot = red[0]+red[1]+red[2]+red[3];
    const float s2 = tot * (1.0f/((float)NQ_*(float)NK_)); // m = 1/784 exact
    a_b[g] = bng_b[g]*rsqrtf(s2 + 1e-3f);
    c_b[g] = bnb_b[g];
  }
}

// corr_b[n] = sum_g c_b[g] * (colsumV_b[g*512:(g+1)*512] . Wo_g[:,n])
__global__ __launch_bounds__(256)
void corr_kernel(const float* __restrict__ cs_b, const u16* __restrict__ Wot,
                 const float* __restrict__ c_b, float* __restrict__ corr_b){
  const int n = blockIdx.x, t = threadIdx.x;
  __shared__ float red[256];
  float s = 0.f;
  for(int hd=t; hd<HD_; hd+=256)
    s += c_b[hd>>9] * cs_b[hd] * b2f(Wot[(long long)n*HD_+hd]);
  red[t]=s; __syncthreads();
  for(int st=128; st>0; st>>=1){ if(t<st) red[t]+=red[t+st]; __syncthreads(); }
  if(t==0) corr_b[n]=red[0];
}

// ---------------------------------------------------------------------------
extern "C" void kernel_launch(void* const* d_in, const int* in_sizes, int n_in,
                              void* d_out, int out_size, void* d_ws, size_t ws_size,
                              hipStream_t stream)
{
  (void)in_sizes; (void)n_in; (void)out_size;
  const float* queries = (const float*)d_in[0];
  const float* Wq  = (const float*)d_in[3];
  const float* bq  = (const float*)d_in[4];
  const float* Wk  = (const float*)d_in[5];
  const float* bk  = (const float*)d_in[6];
  const float* Wv  = (const float*)d_in[7];
  const float* bv  = (const float*)d_in[8];
  const float* Wo  = (const float*)d_in[9];
  const float* bo  = (const float*)d_in[10];
  const float* srk = (const float*)d_in[11];
  const float* srb = (const float*)d_in[12];
  const float* lng = (const float*)d_in[13];
  const float* lnb = (const float*)d_in[14];
  const float* tw  = (const float*)d_in[15];
  // d_in[16] tb: constant over k -> cancels in softmax (exact)
  const float* bng = (const float*)d_in[17];
  const float* bnb = (const float*)d_in[18];
  float* out = (float*)d_out;
  const float QSC = 0.04419417382415922f;   // 1/sqrt(512)

  char* w = (char*)d_ws;
  size_t off = 0;
  auto alloc = [&](size_t bytes)->char*{
    char* p = w + off; off += (bytes + 255) & ~(size_t)255; return p;
  };

  // Tier select: A needs ~202 MB, B needs ~110 MB.
  const bool tierA = (ws_size >= (size_t)210*1024*1024);

  u16* Wqt = (u16*)alloc((size_t)HD_*C_*2);
  u16* Wkt = (u16*)alloc((size_t)HD_*C_*2);
  u16* Wvt = (u16*)alloc((size_t)HD_*C_*2);
  u16* Wot = (u16*)alloc((size_t)C_*HD_*2);
  u16* x   = (u16*)alloc((size_t)B_*NK_*C_*2 + 131072);     // +128K over-read pad
  u16* Qin;       // tier A: full (12544,512); tier B: per-b (3136,512)
  u16* QfU;       // tier A: full (12544,4096); tier B: per-b (3136,4096)
  if(tierA){
    Qin = (u16*)alloc((size_t)B_*NQ_*C_*2);
    QfU = (u16*)alloc((size_t)B_*NQ_*HD_*2);
  } else {
    Qin = (u16*)alloc((size_t)NQ_*C_*2 + 131072);
    QfU = (u16*)alloc((size_t)NQ_*HD_*2);
  }
  u16* Kf_b = (u16*)alloc((size_t)NK_*HD_*2);   // score B-side over-reads into Vf_b
  u16* Vf_b = (u16*)alloc((size_t)NK_*HD_*2);
  u16* Vt_b = (u16*)alloc((size_t)HD_*NKP_*2);
  u16* S_b  = (u16*)alloc((size_t)8*NQ_*NKP_*2 + 262144);   // +256K over-read pad
  float* colsum  = (float*)alloc((size_t)B_*HD_*4);
  float* partial = (float*)alloc((size_t)8*NQ_*4);          // per-(g,qi) sumdev2
  float* aArr    = (float*)alloc(256);
  float* cArr    = (float*)alloc(256);
  float* corrB   = (float*)alloc((size_t)B_*C_*4);

  // ---- weight prep + conv+LN (batch-independent) ----
  wt_kernel<<<dim3(128,16), 256, 0, stream>>>(Wq, Wqt, 512, 4096);
  wt_kernel<<<dim3(128,16), 256, 0, stream>>>(Wk, Wkt, 512, 4096);
  wt_kernel<<<dim3(128,16), 256, 0, stream>>>(Wv, Wvt, 512, 4096);
  wt_kernel<<<dim3(16,128), 256, 0, stream>>>(Wo, Wot, 4096, 512);
  conv_ln<<<B_*NK_, 256, 0, stream>>>(queries, srk, srb, lng, lnb, x);

  if(tierA){
    cvt_bf16<<<6272, 256, 0, stream>>>(queries, Qin, (long long)B_*NQ_*C_);
    // Qf = (queries@Wq + bq)/sqrt(512), full batch
    gemm_bt<0><<<dim3(98,32,1),256,0,stream>>>(Qin, Wqt, QfU, B_*NQ_, 512, 512, 512, HD_,
        1, 0,0,0,0,0,0, bq, QSC, nullptr, nullptr, 1, 0);
  }

  for(int b=0; b<B_; b++){
    u16* Qf_b = tierA ? (QfU + (size_t)b*NQ_*HD_) : QfU;
    if(!tierA){
      cvt_bf16<<<1568, 256, 0, stream>>>(queries + (size_t)b*NQ_*C_, Qin, (long long)NQ_*C_);
      gemm_bt<0><<<dim3(25,32,1),256,0,stream>>>(Qin, Wqt, Qf_b, NQ_, 512, 512, 512, HD_,
          1, 0,0,0,0,0,0, bq, QSC, nullptr, nullptr, 1, 0);
    }
    // K/V projections from LN'd conv output rows of batch b
    const u16* x_b = x + (size_t)b*NK_*C_;
    gemm_bt<0><<<dim3(7,32,1),256,0,stream>>>(x_b, Wkt, Kf_b, NK_, 512, 512, 512, HD_,
        1, 0,0,0,0,0,0, bk, 1.0f, nullptr, nullptr, 1, 0);
    gemm_bt<0><<<dim3(7,32,1),256,0,stream>>>(x_b, Wvt, Vf_b, NK_, 512, 512, 512, HD_,
        1, 0,0,0,0,0,0, bv, 1.0f, nullptr, nullptr, 1, 0);
    vt_kernel<<<dim3(28,128),256,0,stream>>>(Vf_b, Vt_b);
    colsum_v<<<16,256,0,stream>>>(Vf_b, colsum + b*HD_);
    // per-head scores: S_b[h] = Qf_b[:, h*512:+512] @ Kf_b[:, h*512:+512]^T
    gemm_bt<0><<<dim3(25,7,8),256,0,stream>>>(Qf_b, Kf_b, S_b, NQ_, 512, HD_, HD_, NKP_,
        8, 0, 512, 0, 512, 0, (long long)NQ_*NKP_,
        nullptr, 1.0f, nullptr, nullptr, 1, 0);
    mix_softmax<<<NQ_, 512, 0, stream>>>(S_b, tw, partial);
    finalize_stats<<<8,256,0,stream>>>(partial, bng + b*8, bnb + b*8, aArr + b*8, cArr + b*8);
    corr_kernel<<<512,256,0,stream>>>(colsum + b*HD_, Wot, cArr + b*8, corrB + b*C_);
    // U_b[:, g*512+d] = a[b,g] * (P~_g @ V_g)   (overwrites Qf_b; safe: Qf_b dead)
    gemm_bt<0><<<dim3(25,4,8),256,0,stream>>>(S_b, Vt_b, Qf_b, NQ_, NKP_, NKP_, NKP_, HD_,
        8, 0, (long long)NQ_*NKP_, 0, (long long)512*NKP_, 0, 512,
        nullptr, 1.0f, aArr + b*8, nullptr, 1, 0);
    if(!tierA){
      gemm_bt<1><<<dim3(25,4,1),256,0,stream>>>(Qf_b, Wot, out + (size_t)b*NQ_*C_,
          NQ_, HD_, HD_, HD_, C_,
          1, 0,0,0,0,0,0, bo, 1.0f, nullptr, corrB + b*C_, NQ_, C_);
    }
  }

  if(tierA){
    // out = U @ Wo + bo + corr[b,:]
    gemm_bt<1><<<dim3(98,4,1),256,0,stream>>>(QfU, Wot, out, B_*NQ_, HD_, HD_, HD_, C_,
        1, 0,0,0,0,0,0, bo, 1.0f, nullptr, corrB, NQ_, C_);
  }
}

// Round 5
// 1240.080 us; speedup vs baseline: 2.0656x; 1.0251x over previous
//
#include <hip/hip_runtime.h>
#include <hip/hip_bf16.h>
#include <math.h>

typedef unsigned short u16;
typedef __attribute__((ext_vector_type(4))) float f32x4;
typedef __attribute__((ext_vector_type(8))) __bf16 bf16x8;

#define B_    4
#define NQ_   3136
#define C_    512
#define HIMG  56
#define WIMG  56
#define HD_   4096
#define NK_   784
#define NKP_  896

static __device__ __forceinline__ float b2f(u16 u){
  union { unsigned int i; float f; } v; v.i = ((unsigned int)u)<<16; return v.f;
}
static __device__ __forceinline__ u16 f2b(float f){
  union { float f; unsigned int i; } v; v.f = f;
  unsigned int r = v.i + 0x7fffu + ((v.i>>16)&1u);
  return (u16)(r>>16);
}

#define GLD16(gsrc, ldst) __builtin_amdgcn_global_load_lds( \
    (const __attribute__((address_space(1))) void*)(gsrc), \
    (__attribute__((address_space(3))) void*)(ldst), 16, 0, 0)

// ---------------------------------------------------------------------------
// 256x256 8-wave deep-pipelined bf16 GEMM (T3+T4 counted-vmcnt schedule).
// C[m,n] = (sum_k A[m,k]*B[n,k] + bias1[n]) * hscale * scalePtr[z], bf16 out.
// A:(M,K) stride sA; B:(N,K) stride sB. BK=64, 2 LDS buffers (128 KiB total),
// waves 2(M)x4(N), per-wave 128x64 out, 16x16x32 MFMA.
// Schedule per K-tile j (buffer bj=j&1):
//   vmcnt(8 | 0 last) ; s_barrier            -> tile j landed in LDS
//   4 phases: {12x ds_read ; s_barrier ; setprio(1) 16 MFMA setprio(0) ; s_barrier}
//   stage tile j+2 into buffer bj (dead: all reads completed pre-barrier)
// LDS XOR swizzle: chunk' = chunk ^ (row&7), applied on BOTH the pre-swizzled
// global source column (write side, since global_load_lds writes linearly)
// and the ds_read byte address (read side) -> bank-spread b128 reads.
// A/B global loads are NOT masked (caller guarantees over-read slack);
// stores masked by row<M && col<Ncols.
// ---------------------------------------------------------------------------
__global__ __launch_bounds__(512)
void gemm256(const u16* __restrict__ A, const u16* __restrict__ Bm, u16* __restrict__ Cm,
             int M, int Ncols, int K, int sA, int sB, int sC, int zdiv,
             long long zA1, long long zA2, long long zB1, long long zB2,
             long long zC1, long long zC2,
             const float* __restrict__ bias1, float hscale,
             const float* __restrict__ scalePtr)
{
  __shared__ u16 lds[65536];                 // 128 KiB: A@0(2x32K), B@64K(2x32K)
  const int z  = blockIdx.z;
  const int zq = z / zdiv, zr = z % zdiv;
  const u16* Ab = A  + (long long)zq*zA1 + (long long)zr*zA2;
  const u16* Bb = Bm + (long long)zq*zB1 + (long long)zr*zB2;
  const int m0 = blockIdx.x*256, n0 = blockIdx.y*256;
  const int t = threadIdx.x, w = t>>6, lane = t&63;
  const int wm = w>>2, wn = w&3;             // 2 x 4 wave grid
  const int l15 = lane & 15;

  // staging source (pre-swizzled column: involution c ^= row&7)
  const int srow = t>>3;                                   // 0..63
  const int scol = (((t&7) ^ ((t>>3)&7)) << 3);            // elems
  const u16* aS = Ab + (long long)(m0 + srow)*sA + scol;
  const u16* bS = Bb + (long long)(n0 + srow)*sB + scol;
  const long long sA64 = (long long)64*sA, sB64 = (long long)64*sB;
  const int w512 = w*512;                                  // u16 units = 1KB

#define STAGE_TILE(jt, buf) do{                                   \
    const u16* a0_ = aS + (long long)(jt)*64;                     \
    const u16* b0_ = bS + (long long)(jt)*64;                     \
    u16* la_ = lds + (buf)*16384 + w512;                          \
    u16* lb_ = lds + 32768 + (buf)*16384 + w512;                  \
    GLD16(a0_,            la_);                                   \
    GLD16(a0_ +   sA64,   la_ + 4096);                            \
    GLD16(a0_ + 2*sA64,   la_ + 8192);                            \
    GLD16(a0_ + 3*sA64,   la_ + 12288);                           \
    GLD16(b0_,            lb_);                                   \
    GLD16(b0_ +   sB64,   lb_ + 4096);                            \
    GLD16(b0_ + 2*sB64,   lb_ + 8192);                            \
    GLD16(b0_ + 3*sB64,   lb_ + 12288);                           \
  }while(0)

  f32x4 acc[8][4];
#pragma unroll
  for(int i=0;i<8;i++)
#pragma unroll
    for(int j=0;j<4;j++) acc[i][j] = (f32x4)(0.0f);

  const char* ldsc = (const char*)lds;
  const int ck0 = (((lane>>4)     ^ (lane&7)) << 4);   // k32=0 swizzled chunk byte
  const int ck1 = (((4+(lane>>4)) ^ (lane&7)) << 4);   // k32=1
  const int aRowB = (wm*128 + l15) * 128;              // A row byte base (per wave/lane)
  const int bRowB = (wn*64  + l15) * 128;              // B row byte base

  const int T = K >> 6;
  STAGE_TILE(0, 0);
  STAGE_TILE(1, 1);

  for(int j=0; j<T; j++){
    const int bj = j & 1;
    if(j == T-1) asm volatile("s_waitcnt vmcnt(0)" ::: "memory");
    else         asm volatile("s_waitcnt vmcnt(8)" ::: "memory");
    asm volatile("s_barrier" ::: "memory");   // tile j visible to all waves

    const int aBuf = bj*32768 + aRowB;
    const int bBuf = 65536 + bj*32768 + bRowB;
#pragma unroll
    for(int p=0;p<4;p++){
      const int qm = p>>1, qn = p&1;
      bf16x8 af[4][2], bfv[2][2];
      const int aQ = aBuf + qm*8192;          // qm*64 rows * 128B
#pragma unroll
      for(int fr=0; fr<4; fr++){
        af[fr][0] = *(const bf16x8*)(ldsc + aQ + fr*2048 + ck0);
        af[fr][1] = *(const bf16x8*)(ldsc + aQ + fr*2048 + ck1);
      }
      const int bQ = bBuf + qn*4096;          // qn*32 rows * 128B
#pragma unroll
      for(int fn=0; fn<2; fn++){
        bfv[fn][0] = *(const bf16x8*)(ldsc + bQ + fn*2048 + ck0);
        bfv[fn][1] = *(const bf16x8*)(ldsc + bQ + fn*2048 + ck1);
      }
      asm volatile("s_barrier" ::: "memory");
      __builtin_amdgcn_s_setprio(1);
#pragma unroll
      for(int fr=0; fr<4; fr++)
#pragma unroll
        for(int fn=0; fn<2; fn++){
          f32x4 tacc = acc[qm*4+fr][qn*2+fn];
          tacc = __builtin_amdgcn_mfma_f32_16x16x32_bf16(af[fr][0], bfv[fn][0], tacc, 0,0,0);
          tacc = __builtin_amdgcn_mfma_f32_16x16x32_bf16(af[fr][1], bfv[fn][1], tacc, 0,0,0);
          acc[qm*4+fr][qn*2+fn] = tacc;
        }
      __builtin_amdgcn_s_setprio(0);
      asm volatile("s_barrier" ::: "memory");  // buffer-slot reads of phase p done
    }
    if(j+2 < T) STAGE_TILE(j+2, bj);           // buffer bj fully dead here
  }
#undef STAGE_TILE

  const float dsc = scalePtr ? scalePtr[z] : 1.0f;
  const long long cBase = (long long)zq*zC1 + (long long)zr*zC2;
  const int r4 = (lane>>4)*4;
#pragma unroll
  for(int mf=0; mf<8; mf++){
    const int row0 = m0 + wm*128 + mf*16 + r4;
#pragma unroll
    for(int nf=0; nf<4; nf++){
      const int col = n0 + wn*64 + nf*16 + l15;
      if(col < Ncols){
#pragma unroll
        for(int r=0;r<4;r++){
          const int row = row0 + r;
          if(row < M){
            float v = acc[mf][nf][r];
            if(bias1) v += bias1[col];
            Cm[cBase + (long long)row*sC + col] = f2b(v * hscale * dsc);
          }
        }
      }
    }
  }
}

// ---------------------------------------------------------------------------
// old 128x128 GEMM kept for small-grid cases (K/V proj, out-proj)
// ---------------------------------------------------------------------------
template<int OUT_F32>
__global__ __launch_bounds__(256)
void gemm_bt(const u16* __restrict__ A, const u16* __restrict__ Bm, void* __restrict__ Cm,
             int M, int K, int sA, int sB, int sC, int zdiv,
             long long zA1, long long zA2, long long zB1, long long zB2,
             long long zC1, long long zC2,
             const float* __restrict__ bias1, float hscale,
             const float* __restrict__ scalePtr,
             const float* __restrict__ bias2, int rowsPerB, int b2s)
{
  __shared__ u16 lA[128*32];
  __shared__ u16 lB[128*32];
  const int z  = blockIdx.z;
  const int zq = z / zdiv, zr = z % zdiv;
  const u16* Ab = A  + (long long)zq*zA1 + (long long)zr*zA2;
  const u16* Bb = Bm + (long long)zq*zB1 + (long long)zr*zB2;
  const int m0 = blockIdx.x*128, n0 = blockIdx.y*128;
  const int t = threadIdx.x, wave = t>>6, lane = t&63;
  const int wm = (wave>>1)*64, wn = (wave&1)*64;
  const int lrow = t>>2, lcol = (t&3)*8;

  const u16* aSrc = Ab + (long long)(m0+lrow)*sA + lcol;
  const u16* bSrc = Bb + (long long)(n0+lrow)*sB + lcol;
  u16* lAw = lA + wave*512;
  u16* lBw = lB + wave*512;

  f32x4 acc[4][4];
#pragma unroll
  for(int i=0;i<4;i++)
#pragma unroll
    for(int j=0;j<4;j++) acc[i][j] = (f32x4)(0.0f);

  const int l16 = lane & 15, lk8 = (lane>>4)*8;

  for(int kk=0; kk<K; kk+=32){
    GLD16(aSrc,                    lAw);
    GLD16(aSrc + (long long)64*sA, lAw + 64*32);
    GLD16(bSrc,                    lBw);
    GLD16(bSrc + (long long)64*sB, lBw + 64*32);
    aSrc += 32; bSrc += 32;
    __syncthreads();
    bf16x8 af[4], bfr[4];
#pragma unroll
    for(int i=0;i<4;i++){
      af[i]  = *(const bf16x8*)(lA + (wm + i*16 + l16)*32 + lk8);
      bfr[i] = *(const bf16x8*)(lB + (wn + i*16 + l16)*32 + lk8);
    }
#pragma unroll
    for(int i=0;i<4;i++)
#pragma unroll
      for(int j=0;j<4;j++)
        acc[i][j] = __builtin_amdgcn_mfma_f32_16x16x32_bf16(af[i], bfr[j], acc[i][j], 0,0,0);
    __syncthreads();
  }

  const float dsc = scalePtr ? scalePtr[z] : 1.0f;
  const long long cBase = (long long)zq*zC1 + (long long)zr*zC2;
  const int rbase = (lane>>4)*4;
#pragma unroll
  for(int i=0;i<4;i++){
#pragma unroll
    for(int j=0;j<4;j++){
#pragma unroll
      for(int r=0;r<4;r++){
        const int row = m0 + wm + i*16 + rbase + r;
        const int col = n0 + wn + j*16 + l16;
        if(row < M){
          float v = acc[i][j][r];
          if(bias1) v += bias1[col];
          v *= hscale * dsc;
          if(bias2) v += bias2[(row/rowsPerB)*b2s + col];
          if(OUT_F32) ((float*)Cm)[cBase + (long long)row*sC + col] = v;
          else        ((u16*) Cm)[cBase + (long long)row*sC + col] = f2b(v);
        }
      }
    }
  }
}

// f32 (K,N) weight -> bf16 (N,K) transpose
__global__ __launch_bounds__(256)
void wt_kernel(const float* __restrict__ W, u16* __restrict__ Wt, int K, int N){
  __shared__ float tile[32][33];
  const int n0 = blockIdx.x*32, k0 = blockIdx.y*32;
  const int t = threadIdx.x, tr = t>>5, tc = t&31;
#pragma unroll
  for(int i=0;i<4;i++)
    tile[tr+i*8][tc] = W[(long long)(k0+tr+i*8)*N + n0+tc];
  __syncthreads();
#pragma unroll
  for(int i=0;i<4;i++)
    Wt[(long long)(n0+tr+i*8)*K + k0+tc] = f2b(tile[tc][tr+i*8]);
}

__global__ __launch_bounds__(256)
void cvt_bf16(const float* __restrict__ in, u16* __restrict__ outp, long long n){
  long long i = ((long long)blockIdx.x*256 + threadIdx.x)*4;
  if(i+3 < n){
    float4 v = *(const float4*)(in+i);
    ushort4 o; o.x=f2b(v.x); o.y=f2b(v.y); o.z=f2b(v.z); o.w=f2b(v.w);
    *(ushort4*)(outp+i) = o;
  }
}

// depthwise 3x3 stride-2 SAME conv (pad lo=0,hi=1) + bias + LayerNorm -> bf16
__global__ __launch_bounds__(256)
void conv_ln(const float* __restrict__ q, const float* __restrict__ ker,
             const float* __restrict__ cbias, const float* __restrict__ gamma,
             const float* __restrict__ beta, u16* __restrict__ xo)
{
  const int p = blockIdx.x;
  const int b = p / 784, pix = p % 784;
  const int oy = pix / 28, ox = pix % 28;
  const int t = threadIdx.x;
  __shared__ float red[256];
  float v[2];
#pragma unroll
  for(int e=0;e<2;e++){
    const int c = t + e*256;
    float acc = cbias[c];
    for(int ky=0;ky<3;ky++){
      const int y = oy*2 + ky;
      if(y >= HIMG) continue;
      for(int kx=0;kx<3;kx++){
        const int x = ox*2 + kx;
        if(x >= WIMG) continue;
        acc += q[(((long long)b*HIMG + y)*WIMG + x)*C_ + c] * ker[(ky*3+kx)*C_ + c];
      }
    }
    v[e] = acc;
  }
  red[t]=v[0]+v[1]; __syncthreads();
  for(int st=128; st>0; st>>=1){ if(t<st) red[t]+=red[t+st]; __syncthreads(); }
  const float mu = red[0] * (1.0f/C_);
  __syncthreads();
  const float d0=v[0]-mu, d1=v[1]-mu;
  red[t]=d0*d0+d1*d1; __syncthreads();
  for(int st=128; st>0; st>>=1){ if(t<st) red[t]+=red[t+st]; __syncthreads(); }
  const float rs = rsqrtf(red[0]*(1.0f/C_) + 1e-3f);
  const long long ob = (long long)p*C_;
#pragma unroll
  for(int e=0;e<2;e++){
    const int c = t+e*256;
    xo[ob+c] = f2b((v[e]-mu)*rs*gamma[c] + beta[c]);
  }
}

// per-batch: Vf_b (784,4096) -> Vt_b (4096,896) transposed, k zero-padded
__global__ __launch_bounds__(256)
void vt_kernel(const u16* __restrict__ Vf_b, u16* __restrict__ Vt_b){
  __shared__ u16 tile[32][33];
  const int k0 = blockIdx.x*32, d0 = blockIdx.y*32;
  const int t = threadIdx.x, tr = t>>5, tc = t&31;
#pragma unroll
  for(int i=0;i<4;i++){
    const int k = k0+tr+i*8;
    tile[tr+i*8][tc] = (k < NK_) ? Vf_b[(long long)k*HD_ + d0+tc] : (u16)0;
  }
  __syncthreads();
#pragma unroll
  for(int i=0;i<4;i++)
    Vt_b[(long long)(d0+tr+i*8)*NKP_ + k0+tc] = tile[tc][tr+i*8];
}

// ---------------------------------------------------------------------------
// Wave-parallel mix+softmax: one block (512 thr = 8 waves) per q-row.
// Unique-slot partial sums (no hot atomics).
// ---------------------------------------------------------------------------
__global__ __launch_bounds__(512)
void mix_softmax(u16* __restrict__ S_b, const float* __restrict__ tw,
                 float* __restrict__ partial_b)
{
  const int qi = blockIdx.x;
  const int t = threadIdx.x;
  const int wave = t >> 6, lane = t & 63;
  __shared__ float sv[8*NK_];
  const long long rowstr = (long long)NQ_*NKP_;
  const long long base = (long long)qi*NKP_;

  for(int idx = t; idx < 8*196; idx += 512){
    const int h = idx / 196, c4 = idx % 196;
    ushort4 u4 = *(const ushort4*)(S_b + base + h*rowstr + c4*4);
    float* d = sv + h*NK_ + c4*4;
    d[0]=b2f(u4.x); d[1]=b2f(u4.y); d[2]=b2f(u4.z); d[3]=b2f(u4.w);
  }
  __syncthreads();

  const int g = wave;
  float wgt[8];
#pragma unroll
  for(int h=0;h<8;h++) wgt[h] = tw[h*8+g];

  float xs[13];
  float lmax = -1e30f;
#pragma unroll
  for(int j=0;j<13;j++){
    const int k = j*64 + lane;
    if(k < NK_){
      float x = 0.f;
#pragma unroll
      for(int h=0;h<8;h++) x += wgt[h]*sv[h*NK_+k];
      xs[j] = x;
      lmax = fmaxf(lmax, x);
    } else xs[j] = -1e30f;
  }
#pragma unroll
  for(int off=32; off>=1; off>>=1) lmax = fmaxf(lmax, __shfl_xor(lmax, off));

  float lsum = 0.f;
#pragma unroll
  for(int j=0;j<13;j++){
    const int k = j*64 + lane;
    if(k < NK_){
      const float e = __expf(xs[j] - lmax);
      xs[j] = e; lsum += e;
    }
  }
#pragma unroll
  for(int off=32; off>=1; off>>=1) lsum += __shfl_xor(lsum, off);
  const float inv = 1.0f/lsum;

  u16* dst = S_b + base + g*rowstr;
  float lss = 0.f;
#pragma unroll
  for(int j=0;j<13;j++){
    const int k = j*64 + lane;
    if(k < NK_){
      const float dev = xs[j]*inv - (1.0f/NK_);
      dst[k] = f2b(dev);
      lss += dev*dev;
    }
  }
  for(int k = NK_ + lane; k < NKP_; k += 64) dst[k] = 0;
#pragma unroll
  for(int off=32; off>=1; off>>=1) lss += __shfl_xor(lss, off);
  if(lane==0) partial_b[g*NQ_ + qi] = lss;
}

__global__ __launch_bounds__(256)
void colsum_v(const u16* __restrict__ Vf_b, float* __restrict__ cs_b){
  const int hd = blockIdx.x*256 + threadIdx.x;
  const u16* p = Vf_b + hd;
  float s=0.f;
  for(int k=0;k<NK_;k++) s += b2f(p[(long long)k*HD_]);
  cs_b[hd]=s;
}

__global__ __launch_bounds__(256)
void finalize_stats(const float* __restrict__ partial_b, const float* __restrict__ bng_b,
                    const float* __restrict__ bnb_b, float* __restrict__ a_b,
                    float* __restrict__ c_b){
  const int g = blockIdx.x;
  const int t = threadIdx.x;
  __shared__ float red[4];
  float s = 0.f;
  for(int i=t; i<NQ_; i+=256) s += partial_b[g*NQ_ + i];
#pragma unroll
  for(int off=32; off>=1; off>>=1) s += __shfl_xor(s, off);
  if((t&63)==0) red[t>>6] = s;
  __syncthreads();
  if(t==0){
    const float tot = red[0]+red[1]+red[2]+red[3];
    const float s2 = tot * (1.0f/((float)NQ_*(float)NK_));
    a_b[g] = bng_b[g]*rsqrtf(s2 + 1e-3f);
    c_b[g] = bnb_b[g];
  }
}

__global__ __launch_bounds__(256)
void corr_kernel(const float* __restrict__ cs_b, const u16* __restrict__ Wot,
                 const float* __restrict__ c_b, float* __restrict__ corr_b){
  const int n = blockIdx.x, t = threadIdx.x;
  __shared__ float red[256];
  float s = 0.f;
  for(int hd=t; hd<HD_; hd+=256)
    s += c_b[hd>>9] * cs_b[hd] * b2f(Wot[(long long)n*HD_+hd]);
  red[t]=s; __syncthreads();
  for(int st=128; st>0; st>>=1){ if(t<st) red[t]+=red[t+st]; __syncthreads(); }
  if(t==0) corr_b[n]=red[0];
}

// ---------------------------------------------------------------------------
extern "C" void kernel_launch(void* const* d_in, const int* in_sizes, int n_in,
                              void* d_out, int out_size, void* d_ws, size_t ws_size,
                              hipStream_t stream)
{
  (void)in_sizes; (void)n_in; (void)out_size;
  const float* queries = (const float*)d_in[0];
  const float* Wq  = (const float*)d_in[3];
  const float* bq  = (const float*)d_in[4];
  const float* Wk  = (const float*)d_in[5];
  const float* bk  = (const float*)d_in[6];
  const float* Wv  = (const float*)d_in[7];
  const float* bv  = (const float*)d_in[8];
  const float* Wo  = (const float*)d_in[9];
  const float* bo  = (const float*)d_in[10];
  const float* srk = (const float*)d_in[11];
  const float* srb = (const float*)d_in[12];
  const float* lng = (const float*)d_in[13];
  const float* lnb = (const float*)d_in[14];
  const float* tw  = (const float*)d_in[15];
  const float* bng = (const float*)d_in[17];
  const float* bnb = (const float*)d_in[18];
  float* out = (float*)d_out;
  const float QSC = 0.04419417382415922f;   // 1/sqrt(512)

  char* w = (char*)d_ws;
  size_t off = 0;
  auto alloc = [&](size_t bytes)->char*{
    char* p = w + off; off += (bytes + 255) & ~(size_t)255; return p;
  };

  const bool tierA = (ws_size >= (size_t)210*1024*1024);

  u16* Wqt = (u16*)alloc((size_t)HD_*C_*2);
  u16* Wkt = (u16*)alloc((size_t)HD_*C_*2);
  u16* Wvt = (u16*)alloc((size_t)HD_*C_*2);
  u16* Wot = (u16*)alloc((size_t)C_*HD_*2);
  u16* x   = (u16*)alloc((size_t)B_*NK_*C_*2 + 131072);
  u16* Qin;
  u16* QfU;
  if(tierA){
    Qin = (u16*)alloc((size_t)B_*NQ_*C_*2);
    QfU = (u16*)alloc((size_t)B_*NQ_*HD_*2);
  } else {
    Qin = (u16*)alloc((size_t)NQ_*C_*2 + 262144);
    QfU = (u16*)alloc((size_t)NQ_*HD_*2);
  }
  u16* Kf_b = (u16*)alloc((size_t)NK_*HD_*2);
  u16* Vf_b = (u16*)alloc((size_t)NK_*HD_*2);
  u16* Vt_b = (u16*)alloc((size_t)HD_*NKP_*2);
  u16* S_b  = (u16*)alloc((size_t)8*NQ_*NKP_*2 + 524288);   // +512K: PV 256-tile A over-read
  float* colsum  = (float*)alloc((size_t)B_*HD_*4);
  float* partial = (float*)alloc((size_t)8*NQ_*4);
  float* aArr    = (float*)alloc(256);
  float* cArr    = (float*)alloc(256);
  float* corrB   = (float*)alloc((size_t)B_*C_*4);

  // ---- weight prep + conv+LN ----
  wt_kernel<<<dim3(128,16), 256, 0, stream>>>(Wq, Wqt, 512, 4096);
  wt_kernel<<<dim3(128,16), 256, 0, stream>>>(Wk, Wkt, 512, 4096);
  wt_kernel<<<dim3(128,16), 256, 0, stream>>>(Wv, Wvt, 512, 4096);
  wt_kernel<<<dim3(16,128), 256, 0, stream>>>(Wo, Wot, 4096, 512);
  conv_ln<<<B_*NK_, 256, 0, stream>>>(queries, srk, srb, lng, lnb, x);

  if(tierA){
    cvt_bf16<<<6272, 256, 0, stream>>>(queries, Qin, (long long)B_*NQ_*C_);
    // Qf = (queries@Wq + bq)/sqrt(512): 256-tile deep-pipelined GEMM
    gemm256<<<dim3(49,16,1),512,0,stream>>>(Qin, Wqt, QfU, B_*NQ_, 4096, 512,
        512, 512, HD_, 1, 0,0,0,0,0,0, bq, QSC, nullptr);
  }

  for(int b=0; b<B_; b++){
    u16* Qf_b = tierA ? (QfU + (size_t)b*NQ_*HD_) : QfU;
    if(!tierA){
      cvt_bf16<<<1568, 256, 0, stream>>>(queries + (size_t)b*NQ_*C_, Qin, (long long)NQ_*C_);
      gemm256<<<dim3(13,16,1),512,0,stream>>>(Qin, Wqt, Qf_b, NQ_, 4096, 512,
          512, 512, HD_, 1, 0,0,0,0,0,0, bq, QSC, nullptr);
    }
    const u16* x_b = x + (size_t)b*NK_*C_;
    gemm_bt<0><<<dim3(7,32,1),256,0,stream>>>(x_b, Wkt, Kf_b, NK_, 512, 512, 512, HD_,
        1, 0,0,0,0,0,0, bk, 1.0f, nullptr, nullptr, 1, 0);
    gemm_bt<0><<<dim3(7,32,1),256,0,stream>>>(x_b, Wvt, Vf_b, NK_, 512, 512, 512, HD_,
        1, 0,0,0,0,0,0, bv, 1.0f, nullptr, nullptr, 1, 0);
    vt_kernel<<<dim3(28,128),256,0,stream>>>(Vf_b, Vt_b);
    colsum_v<<<16,256,0,stream>>>(Vf_b, colsum + b*HD_);
    // per-head scores: S_b[z] = Qf_b[:, z*512:+512] @ Kf_b[:, z*512:+512]^T
    gemm256<<<dim3(13,4,8),512,0,stream>>>(Qf_b, Kf_b, S_b, NQ_, NKP_, 512,
        HD_, HD_, NKP_, 8, 0, 512, 0, 512, 0, (long long)NQ_*NKP_,
        nullptr, 1.0f, nullptr);
    mix_softmax<<<NQ_, 512, 0, stream>>>(S_b, tw, partial);
    finalize_stats<<<8,256,0,stream>>>(partial, bng + b*8, bnb + b*8, aArr + b*8, cArr + b*8);
    corr_kernel<<<512,256,0,stream>>>(colsum + b*HD_, Wot, cArr + b*8, corrB + b*C_);
    // U_b[:, z*512+d] = a[b,z] * (P~_z @ V_z)
    gemm256<<<dim3(13,2,8),512,0,stream>>>(S_b, Vt_b, Qf_b, NQ_, 512, NKP_,
        NKP_, NKP_, HD_, 8, 0, (long long)NQ_*NKP_, 0, (long long)512*NKP_, 0, 512,
        nullptr, 1.0f, aArr + b*8);
    if(!tierA){
      gemm_bt<1><<<dim3(25,4,1),256,0,stream>>>(Qf_b, Wot, out + (size_t)b*NQ_*C_,
          NQ_, HD_, HD_, HD_, C_,
          1, 0,0,0,0,0,0, bo, 1.0f, nullptr, corrB + b*C_, NQ_, C_);
    }
  }

  if(tierA){
    gemm_bt<1><<<dim3(98,4,1),256,0,stream>>>(QfU, Wot, out, B_*NQ_, HD_, HD_, HD_, C_,
        1, 0,0,0,0,0,0, bo, 1.0f, nullptr, corrB, NQ_, C_);
  }
}

// Round 6
// 1157.613 us; speedup vs baseline: 2.2127x; 1.0712x over previous
//
#include <hip/hip_runtime.h>
#include <hip/hip_bf16.h>
#include <math.h>

typedef unsigned short u16;
typedef __attribute__((ext_vector_type(4))) float f32x4;
typedef __attribute__((ext_vector_type(8))) __bf16 bf16x8;

#define B_    4
#define NQ_   3136
#define C_    512
#define HIMG  56
#define WIMG  56
#define HD_   4096
#define NK_   784
#define NKP_  896

static __device__ __forceinline__ float b2f(u16 u){
  union { unsigned int i; float f; } v; v.i = ((unsigned int)u)<<16; return v.f;
}
static __device__ __forceinline__ u16 f2b(float f){
  union { float f; unsigned int i; } v; v.f = f;
  unsigned int r = v.i + 0x7fffu + ((v.i>>16)&1u);
  return (u16)(r>>16);
}

#define GLD16(gsrc, ldst) __builtin_amdgcn_global_load_lds( \
    (const __attribute__((address_space(1))) void*)(gsrc), \
    (__attribute__((address_space(3))) void*)(ldst), 16, 0, 0)

// ---------------------------------------------------------------------------
// 256x256 8-wave bf16 GEMM, v2: non-redundant fragment reads.
// C[m,n] = (sum_k A[m,k]*B[n,k] + bias1[n]) * hscale * scalePtr[z], bf16 out.
// BK=64, double-buffered 128 KiB LDS, waves 2(M)x4(N), wave tile 128x64.
// Per K-tile j (buffer bj=j&1):
//   s_waitcnt vmcnt(8|0last) ; s_barrier          -> tile j landed
//   2 k-half phases: {12x ds_read_b128 (af[8],bf[4], each frag ONCE)
//                     setprio(1) 32 MFMA setprio(0)}   (no barrier between)
//   s_barrier                                     -> all reads of buf bj done
//   STAGE(j+2 -> buf bj)
// 24 KB ds_read per wave per K-tile (minimal) vs 48 KB in v1; 2 barriers vs 9.
// XOR swizzle (chunk ^= row&7) on both pre-swizzled global source and read
// address -> verified even bank distribution (8 hits/bank per wave-read).
// A/B loads NOT masked (caller guarantees over-read slack); stores masked.
// Requires K%64==0, K>=192 (2-deep prefetch prologue).
// ---------------------------------------------------------------------------
__global__ __launch_bounds__(512)
void gemm256(const u16* __restrict__ A, const u16* __restrict__ Bm, u16* __restrict__ Cm,
             int M, int Ncols, int K, int sA, int sB, int sC, int zdiv,
             long long zA1, long long zA2, long long zB1, long long zB2,
             long long zC1, long long zC2,
             const float* __restrict__ bias1, float hscale,
             const float* __restrict__ scalePtr)
{
  __shared__ u16 lds[65536];                 // A: 2x32K @0, B: 2x32K @64K (bytes)
  const int z  = blockIdx.z;
  const int zq = z / zdiv, zr = z % zdiv;
  const u16* Ab = A  + (long long)zq*zA1 + (long long)zr*zA2;
  const u16* Bb = Bm + (long long)zq*zB1 + (long long)zr*zB2;
  const int m0 = blockIdx.x*256, n0 = blockIdx.y*256;
  const int t = threadIdx.x, w = t>>6, lane = t&63;
  const int wm = w>>2, wn = w&3;             // 2 x 4 wave grid
  const int l15 = lane & 15;

  // staging source (pre-swizzled column: involution c ^= row&7)
  const int srow = t>>3;                                   // 0..63
  const int scol = (((t&7) ^ ((t>>3)&7)) << 3);            // elems
  const u16* aS = Ab + (long long)(m0 + srow)*sA + scol;
  const u16* bS = Bb + (long long)(n0 + srow)*sB + scol;
  const long long sA64 = (long long)64*sA, sB64 = (long long)64*sB;
  const int w512 = w*512;                                  // u16 units = 1KB

#define STAGE_TILE(jt, buf) do{                                   \
    const u16* a0_ = aS + (long long)(jt)*64;                     \
    const u16* b0_ = bS + (long long)(jt)*64;                     \
    u16* la_ = lds + (buf)*16384 + w512;                          \
    u16* lb_ = lds + 32768 + (buf)*16384 + w512;                  \
    GLD16(a0_,            la_);                                   \
    GLD16(a0_ +   sA64,   la_ + 4096);                            \
    GLD16(a0_ + 2*sA64,   la_ + 8192);                            \
    GLD16(a0_ + 3*sA64,   la_ + 12288);                           \
    GLD16(b0_,            lb_);                                   \
    GLD16(b0_ +   sB64,   lb_ + 4096);                            \
    GLD16(b0_ + 2*sB64,   lb_ + 8192);                            \
    GLD16(b0_ + 3*sB64,   lb_ + 12288);                           \
  }while(0)

  f32x4 acc[8][4];
#pragma unroll
  for(int i=0;i<8;i++)
#pragma unroll
    for(int j=0;j<4;j++) acc[i][j] = (f32x4)(0.0f);

  const char* ldsc = (const char*)lds;
  const int ck0 = (((lane>>4)     ^ (lane&7)) << 4);   // k-half 0 swizzled chunk
  const int ck1 = (((4+(lane>>4)) ^ (lane&7)) << 4);   // k-half 1
  const int aRowB = (wm*128 + l15) * 128;              // A row byte base
  const int bRowB = (wn*64  + l15) * 128;              // B row byte base

  const int T = K >> 6;
  STAGE_TILE(0, 0);
  STAGE_TILE(1, 1);

  for(int j=0; j<T; j++){
    const int bj = j & 1;
    if(j == T-1) asm volatile("s_waitcnt vmcnt(0)" ::: "memory");
    else         asm volatile("s_waitcnt vmcnt(8)" ::: "memory");
    asm volatile("s_barrier" ::: "memory");   // tile j visible to all waves

    const int aBuf = bj*32768 + aRowB;
    const int bBuf = 65536 + bj*32768 + bRowB;
    {
      bf16x8 af[8], bf[4];
#pragma unroll
      for(int fr=0; fr<8; fr++) af[fr] = *(const bf16x8*)(ldsc + aBuf + fr*2048 + ck0);
#pragma unroll
      for(int fn=0; fn<4; fn++) bf[fn] = *(const bf16x8*)(ldsc + bBuf + fn*2048 + ck0);
      __builtin_amdgcn_s_setprio(1);
#pragma unroll
      for(int fr=0; fr<8; fr++)
#pragma unroll
        for(int fn=0; fn<4; fn++)
          acc[fr][fn] = __builtin_amdgcn_mfma_f32_16x16x32_bf16(af[fr], bf[fn], acc[fr][fn], 0,0,0);
      __builtin_amdgcn_s_setprio(0);
    }
    {
      bf16x8 af[8], bf[4];
#pragma unroll
      for(int fr=0; fr<8; fr++) af[fr] = *(const bf16x8*)(ldsc + aBuf + fr*2048 + ck1);
#pragma unroll
      for(int fn=0; fn<4; fn++) bf[fn] = *(const bf16x8*)(ldsc + bBuf + fn*2048 + ck1);
      __builtin_amdgcn_s_setprio(1);
#pragma unroll
      for(int fr=0; fr<8; fr++)
#pragma unroll
        for(int fn=0; fn<4; fn++)
          acc[fr][fn] = __builtin_amdgcn_mfma_f32_16x16x32_bf16(af[fr], bf[fn], acc[fr][fn], 0,0,0);
      __builtin_amdgcn_s_setprio(0);
    }
    asm volatile("s_barrier" ::: "memory");  // all reads of buffer bj complete
    if(j+2 < T) STAGE_TILE(j+2, bj);
  }
#undef STAGE_TILE

  const float dsc = scalePtr ? scalePtr[z] : 1.0f;
  const long long cBase = (long long)zq*zC1 + (long long)zr*zC2;
  const int r4 = (lane>>4)*4;
#pragma unroll
  for(int mf=0; mf<8; mf++){
    const int row0 = m0 + wm*128 + mf*16 + r4;
#pragma unroll
    for(int nf=0; nf<4; nf++){
      const int col = n0 + wn*64 + nf*16 + l15;
      if(col < Ncols){
#pragma unroll
        for(int r=0;r<4;r++){
          const int row = row0 + r;
          if(row < M){
            float v = acc[mf][nf][r];
            if(bias1) v += bias1[col];
            Cm[cBase + (long long)row*sC + col] = f2b(v * hscale * dsc);
          }
        }
      }
    }
  }
}

// ---------------------------------------------------------------------------
// old 128x128 GEMM kept for out-proj (K=4096: well-amortized regime)
// ---------------------------------------------------------------------------
template<int OUT_F32>
__global__ __launch_bounds__(256)
void gemm_bt(const u16* __restrict__ A, const u16* __restrict__ Bm, void* __restrict__ Cm,
             int M, int K, int sA, int sB, int sC, int zdiv,
             long long zA1, long long zA2, long long zB1, long long zB2,
             long long zC1, long long zC2,
             const float* __restrict__ bias1, float hscale,
             const float* __restrict__ scalePtr,
             const float* __restrict__ bias2, int rowsPerB, int b2s)
{
  __shared__ u16 lA[128*32];
  __shared__ u16 lB[128*32];
  const int z  = blockIdx.z;
  const int zq = z / zdiv, zr = z % zdiv;
  const u16* Ab = A  + (long long)zq*zA1 + (long long)zr*zA2;
  const u16* Bb = Bm + (long long)zq*zB1 + (long long)zr*zB2;
  const int m0 = blockIdx.x*128, n0 = blockIdx.y*128;
  const int t = threadIdx.x, wave = t>>6, lane = t&63;
  const int wm = (wave>>1)*64, wn = (wave&1)*64;
  const int lrow = t>>2, lcol = (t&3)*8;

  const u16* aSrc = Ab + (long long)(m0+lrow)*sA + lcol;
  const u16* bSrc = Bb + (long long)(n0+lrow)*sB + lcol;
  u16* lAw = lA + wave*512;
  u16* lBw = lB + wave*512;

  f32x4 acc[4][4];
#pragma unroll
  for(int i=0;i<4;i++)
#pragma unroll
    for(int j=0;j<4;j++) acc[i][j] = (f32x4)(0.0f);

  const int l16 = lane & 15, lk8 = (lane>>4)*8;

  for(int kk=0; kk<K; kk+=32){
    GLD16(aSrc,                    lAw);
    GLD16(aSrc + (long long)64*sA, lAw + 64*32);
    GLD16(bSrc,                    lBw);
    GLD16(bSrc + (long long)64*sB, lBw + 64*32);
    aSrc += 32; bSrc += 32;
    __syncthreads();
    bf16x8 af[4], bfr[4];
#pragma unroll
    for(int i=0;i<4;i++){
      af[i]  = *(const bf16x8*)(lA + (wm + i*16 + l16)*32 + lk8);
      bfr[i] = *(const bf16x8*)(lB + (wn + i*16 + l16)*32 + lk8);
    }
#pragma unroll
    for(int i=0;i<4;i++)
#pragma unroll
      for(int j=0;j<4;j++)
        acc[i][j] = __builtin_amdgcn_mfma_f32_16x16x32_bf16(af[i], bfr[j], acc[i][j], 0,0,0);
    __syncthreads();
  }

  const float dsc = scalePtr ? scalePtr[z] : 1.0f;
  const long long cBase = (long long)zq*zC1 + (long long)zr*zC2;
  const int rbase = (lane>>4)*4;
#pragma unroll
  for(int i=0;i<4;i++){
#pragma unroll
    for(int j=0;j<4;j++){
#pragma unroll
      for(int r=0;r<4;r++){
        const int row = m0 + wm + i*16 + rbase + r;
        const int col = n0 + wn + j*16 + l16;
        if(row < M){
          float v = acc[i][j][r];
          if(bias1) v += bias1[col];
          v *= hscale * dsc;
          if(bias2) v += bias2[(row/rowsPerB)*b2s + col];
          if(OUT_F32) ((float*)Cm)[cBase + (long long)row*sC + col] = v;
          else        ((u16*) Cm)[cBase + (long long)row*sC + col] = f2b(v);
        }
      }
    }
  }
}

// f32 (K,N) weight -> bf16 (N,K) transpose
__global__ __launch_bounds__(256)
void wt_kernel(const float* __restrict__ W, u16* __restrict__ Wt, int K, int N){
  __shared__ float tile[32][33];
  const int n0 = blockIdx.x*32, k0 = blockIdx.y*32;
  const int t = threadIdx.x, tr = t>>5, tc = t&31;
#pragma unroll
  for(int i=0;i<4;i++)
    tile[tr+i*8][tc] = W[(long long)(k0+tr+i*8)*N + n0+tc];
  __syncthreads();
#pragma unroll
  for(int i=0;i<4;i++)
    Wt[(long long)(n0+tr+i*8)*K + k0+tc] = f2b(tile[tc][tr+i*8]);
}

__global__ __launch_bounds__(256)
void cvt_bf16(const float* __restrict__ in, u16* __restrict__ outp, long long n){
  long long i = ((long long)blockIdx.x*256 + threadIdx.x)*4;
  if(i+3 < n){
    float4 v = *(const float4*)(in+i);
    ushort4 o; o.x=f2b(v.x); o.y=f2b(v.y); o.z=f2b(v.z); o.w=f2b(v.w);
    *(ushort4*)(outp+i) = o;
  }
}

// depthwise 3x3 stride-2 SAME conv (pad lo=0,hi=1) + bias + LayerNorm -> bf16
__global__ __launch_bounds__(256)
void conv_ln(const float* __restrict__ q, const float* __restrict__ ker,
             const float* __restrict__ cbias, const float* __restrict__ gamma,
             const float* __restrict__ beta, u16* __restrict__ xo)
{
  const int p = blockIdx.x;
  const int b = p / 784, pix = p % 784;
  const int oy = pix / 28, ox = pix % 28;
  const int t = threadIdx.x;
  __shared__ float red[256];
  float v[2];
#pragma unroll
  for(int e=0;e<2;e++){
    const int c = t + e*256;
    float acc = cbias[c];
    for(int ky=0;ky<3;ky++){
      const int y = oy*2 + ky;
      if(y >= HIMG) continue;
      for(int kx=0;kx<3;kx++){
        const int x = ox*2 + kx;
        if(x >= WIMG) continue;
        acc += q[(((long long)b*HIMG + y)*WIMG + x)*C_ + c] * ker[(ky*3+kx)*C_ + c];
      }
    }
    v[e] = acc;
  }
  red[t]=v[0]+v[1]; __syncthreads();
  for(int st=128; st>0; st>>=1){ if(t<st) red[t]+=red[t+st]; __syncthreads(); }
  const float mu = red[0] * (1.0f/C_);
  __syncthreads();
  const float d0=v[0]-mu, d1=v[1]-mu;
  red[t]=d0*d0+d1*d1; __syncthreads();
  for(int st=128; st>0; st>>=1){ if(t<st) red[t]+=red[t+st]; __syncthreads(); }
  const float rs = rsqrtf(red[0]*(1.0f/C_) + 1e-3f);
  const long long ob = (long long)p*C_;
#pragma unroll
  for(int e=0;e<2;e++){
    const int c = t+e*256;
    xo[ob+c] = f2b((v[e]-mu)*rs*gamma[c] + beta[c]);
  }
}

// per-batch: V part of KV_b (784 x 4096, row stride sV) -> Vt_b (4096,896), k zero-padded
__global__ __launch_bounds__(256)
void vt_kernel(const u16* __restrict__ Vf_b, u16* __restrict__ Vt_b, int sV){
  __shared__ u16 tile[32][33];
  const int k0 = blockIdx.x*32, d0 = blockIdx.y*32;
  const int t = threadIdx.x, tr = t>>5, tc = t&31;
#pragma unroll
  for(int i=0;i<4;i++){
    const int k = k0+tr+i*8;
    tile[tr+i*8][tc] = (k < NK_) ? Vf_b[(long long)k*sV + d0+tc] : (u16)0;
  }
  __syncthreads();
#pragma unroll
  for(int i=0;i<4;i++)
    Vt_b[(long long)(d0+tr+i*8)*NKP_ + k0+tc] = tile[tc][tr+i*8];
}

// ---------------------------------------------------------------------------
// Wave-parallel mix+softmax: one block (512 thr = 8 waves) per q-row.
// Unique-slot partial sums (no hot atomics).
// ---------------------------------------------------------------------------
__global__ __launch_bounds__(512)
void mix_softmax(u16* __restrict__ S_b, const float* __restrict__ tw,
                 float* __restrict__ partial_b)
{
  const int qi = blockIdx.x;
  const int t = threadIdx.x;
  const int wave = t >> 6, lane = t & 63;
  __shared__ float sv[8*NK_];
  const long long rowstr = (long long)NQ_*NKP_;
  const long long base = (long long)qi*NKP_;

  for(int idx = t; idx < 8*196; idx += 512){
    const int h = idx / 196, c4 = idx % 196;
    ushort4 u4 = *(const ushort4*)(S_b + base + h*rowstr + c4*4);
    float* d = sv + h*NK_ + c4*4;
    d[0]=b2f(u4.x); d[1]=b2f(u4.y); d[2]=b2f(u4.z); d[3]=b2f(u4.w);
  }
  __syncthreads();

  const int g = wave;
  float wgt[8];
#pragma unroll
  for(int h=0;h<8;h++) wgt[h] = tw[h*8+g];

  float xs[13];
  float lmax = -1e30f;
#pragma unroll
  for(int j=0;j<13;j++){
    const int k = j*64 + lane;
    if(k < NK_){
      float x = 0.f;
#pragma unroll
      for(int h=0;h<8;h++) x += wgt[h]*sv[h*NK_+k];
      xs[j] = x;
      lmax = fmaxf(lmax, x);
    } else xs[j] = -1e30f;
  }
#pragma unroll
  for(int off=32; off>=1; off>>=1) lmax = fmaxf(lmax, __shfl_xor(lmax, off));

  float lsum = 0.f;
#pragma unroll
  for(int j=0;j<13;j++){
    const int k = j*64 + lane;
    if(k < NK_){
      const float e = __expf(xs[j] - lmax);
      xs[j] = e; lsum += e;
    }
  }
#pragma unroll
  for(int off=32; off>=1; off>>=1) lsum += __shfl_xor(lsum, off);
  const float inv = 1.0f/lsum;

  u16* dst = S_b + base + g*rowstr;
  float lss = 0.f;
#pragma unroll
  for(int j=0;j<13;j++){
    const int k = j*64 + lane;
    if(k < NK_){
      const float dev = xs[j]*inv - (1.0f/NK_);
      dst[k] = f2b(dev);
      lss += dev*dev;
    }
  }
  for(int k = NK_ + lane; k < NKP_; k += 64) dst[k] = 0;
#pragma unroll
  for(int off=32; off>=1; off>>=1) lss += __shfl_xor(lss, off);
  if(lane==0) partial_b[g*NQ_ + qi] = lss;
}

__global__ __launch_bounds__(256)
void colsum_v(const u16* __restrict__ Vf_b, float* __restrict__ cs_b, int sV){
  const int hd = blockIdx.x*256 + threadIdx.x;
  const u16* p = Vf_b + hd;
  float s=0.f;
  for(int k=0;k<NK_;k++) s += b2f(p[(long long)k*sV]);
  cs_b[hd]=s;
}

__global__ __launch_bounds__(256)
void finalize_stats(const float* __restrict__ partial_b, const float* __restrict__ bng_b,
                    const float* __restrict__ bnb_b, float* __restrict__ a_b,
                    float* __restrict__ c_b){
  const int g = blockIdx.x;
  const int t = threadIdx.x;
  __shared__ float red[4];
  float s = 0.f;
  for(int i=t; i<NQ_; i+=256) s += partial_b[g*NQ_ + i];
#pragma unroll
  for(int off=32; off>=1; off>>=1) s += __shfl_xor(s, off);
  if((t&63)==0) red[t>>6] = s;
  __syncthreads();
  if(t==0){
    const float tot = red[0]+red[1]+red[2]+red[3];
    const float s2 = tot * (1.0f/((float)NQ_*(float)NK_));
    a_b[g] = bng_b[g]*rsqrtf(s2 + 1e-3f);
    c_b[g] = bnb_b[g];
  }
}

__global__ __launch_bounds__(256)
void corr_kernel(const float* __restrict__ cs_b, const u16* __restrict__ Wot,
                 const float* __restrict__ c_b, float* __restrict__ corr_b){
  const int n = blockIdx.x, t = threadIdx.x;
  __shared__ float red[256];
  float s = 0.f;
  for(int hd=t; hd<HD_; hd+=256)
    s += c_b[hd>>9] * cs_b[hd] * b2f(Wot[(long long)n*HD_+hd]);
  red[t]=s; __syncthreads();
  for(int st=128; st>0; st>>=1){ if(t<st) red[t]+=red[t+st]; __syncthreads(); }
  if(t==0) corr_b[n]=red[0];
}

// ---------------------------------------------------------------------------
extern "C" void kernel_launch(void* const* d_in, const int* in_sizes, int n_in,
                              void* d_out, int out_size, void* d_ws, size_t ws_size,
                              hipStream_t stream)
{
  (void)in_sizes; (void)n_in; (void)out_size;
  const float* queries = (const float*)d_in[0];
  const float* Wq  = (const float*)d_in[3];
  const float* bq  = (const float*)d_in[4];
  const float* Wk  = (const float*)d_in[5];
  const float* bk  = (const float*)d_in[6];
  const float* Wv  = (const float*)d_in[7];
  const float* bv  = (const float*)d_in[8];
  const float* Wo  = (const float*)d_in[9];
  const float* bo  = (const float*)d_in[10];
  const float* srk = (const float*)d_in[11];
  const float* srb = (const float*)d_in[12];
  const float* lng = (const float*)d_in[13];
  const float* lnb = (const float*)d_in[14];
  const float* tw  = (const float*)d_in[15];
  const float* bng = (const float*)d_in[17];
  const float* bnb = (const float*)d_in[18];
  float* out = (float*)d_out;
  const float QSC = 0.04419417382415922f;   // 1/sqrt(512)

  char* w = (char*)d_ws;
  size_t off = 0;
  auto alloc = [&](size_t bytes)->char*{
    char* p = w + off; off += (bytes + 255) & ~(size_t)255; return p;
  };

  const bool tierA = (ws_size >= (size_t)210*1024*1024);

  // bkbv[n] for combined K/V projection bias (n<4096 -> bk, else bv): we pass
  // per-launch; gemm256 bias1 indexes col 0..8191. Build a tiny device array?
  // Simpler: bk and bv are separate inputs; bias lookup done via two launches
  // would defeat the merge. Instead note bk/bv are both 4096 floats and
  // CONTIGUOUS ONLY if the harness packed them so -- not guaranteed. We fold
  // biases with a small fixup kernel-free trick: bias1=nullptr for KV gemm and
  // add biases in downstream consumers? Downstream (score/vt/colsum) would all
  // need it. Cheapest correct option: copy bk||bv into ws once per launch.
  u16* Wqt = (u16*)alloc((size_t)HD_*C_*2);
  u16* Wkt = (u16*)alloc((size_t)HD_*C_*2);   // Wvt must follow contiguously
  u16* Wvt = (u16*)alloc((size_t)HD_*C_*2);
  u16* Wot = (u16*)alloc((size_t)C_*HD_*2);
  u16* x   = (u16*)alloc((size_t)B_*NK_*C_*2 + 262144);     // +256K staging over-read pad
  float* bkv = (float*)alloc((size_t)2*HD_*4);              // bk || bv
  u16* Qin;
  u16* QfU;
  if(tierA){
    Qin = (u16*)alloc((size_t)B_*NQ_*C_*2);
    QfU = (u16*)alloc((size_t)B_*NQ_*HD_*2);
  } else {
    Qin = (u16*)alloc((size_t)NQ_*C_*2 + 262144);
    QfU = (u16*)alloc((size_t)NQ_*HD_*2);
  }
  u16* KV_b = (u16*)alloc((size_t)NK_*2*HD_*2);  // 784 x 8192: [k | v] per row
  u16* Vt_b = (u16*)alloc((size_t)HD_*NKP_*2);
  u16* S_b  = (u16*)alloc((size_t)8*NQ_*NKP_*2 + 524288);   // +512K PV A over-read pad
  float* colsum  = (float*)alloc((size_t)B_*HD_*4);
  float* partial = (float*)alloc((size_t)8*NQ_*4);
  float* aArr    = (float*)alloc(256);
  float* cArr    = (float*)alloc(256);
  float* corrB   = (float*)alloc((size_t)B_*C_*4);

  // ---- weight prep + conv+LN ----
  wt_kernel<<<dim3(128,16), 256, 0, stream>>>(Wq, Wqt, 512, 4096);
  wt_kernel<<<dim3(128,16), 256, 0, stream>>>(Wk, Wkt, 512, 4096);
  wt_kernel<<<dim3(128,16), 256, 0, stream>>>(Wv, Wvt, 512, 4096);
  wt_kernel<<<dim3(16,128), 256, 0, stream>>>(Wo, Wot, 4096, 512);
  conv_ln<<<B_*NK_, 256, 0, stream>>>(queries, srk, srb, lng, lnb, x);
  hipMemcpyAsync(bkv,      bk, HD_*4, hipMemcpyDeviceToDevice, stream);
  hipMemcpyAsync(bkv+HD_,  bv, HD_*4, hipMemcpyDeviceToDevice, stream);

  if(tierA){
    cvt_bf16<<<6272, 256, 0, stream>>>(queries, Qin, (long long)B_*NQ_*C_);
    // Qf = (queries@Wq + bq)/sqrt(512)
    gemm256<<<dim3(49,16,1),512,0,stream>>>(Qin, Wqt, QfU, B_*NQ_, 4096, 512,
        512, 512, HD_, 1, 0,0,0,0,0,0, bq, QSC, nullptr);
  }

  for(int b=0; b<B_; b++){
    u16* Qf_b = tierA ? (QfU + (size_t)b*NQ_*HD_) : QfU;
    if(!tierA){
      cvt_bf16<<<1568, 256, 0, stream>>>(queries + (size_t)b*NQ_*C_, Qin, (long long)NQ_*C_);
      gemm256<<<dim3(13,16,1),512,0,stream>>>(Qin, Wqt, Qf_b, NQ_, 4096, 512,
          512, 512, HD_, 1, 0,0,0,0,0,0, bq, QSC, nullptr);
    }
    const u16* x_b = x + (size_t)b*NK_*C_;
    // combined K|V projection: B spans Wkt..Wvt (adjacent, 8192 rows)
    gemm256<<<dim3(4,32,1),512,0,stream>>>(x_b, Wkt, KV_b, NK_, 2*HD_, 512,
        512, 512, 2*HD_, 1, 0,0,0,0,0,0, bkv, 1.0f, nullptr);
    vt_kernel<<<dim3(28,128),256,0,stream>>>(KV_b + HD_, Vt_b, 2*HD_);
    colsum_v<<<16,256,0,stream>>>(KV_b + HD_, colsum + b*HD_, 2*HD_);
    // per-head scores: S_b[z] = Qf_b[:, z*512:+512] @ K_b[:, z*512:+512]^T
    gemm256<<<dim3(13,4,8),512,0,stream>>>(Qf_b, KV_b, S_b, NQ_, NKP_, 512,
        HD_, 2*HD_, NKP_, 8, 0, 512, 0, 512, 0, (long long)NQ_*NKP_,
        nullptr, 1.0f, nullptr);
    mix_softmax<<<NQ_, 512, 0, stream>>>(S_b, tw, partial);
    finalize_stats<<<8,256,0,stream>>>(partial, bng + b*8, bnb + b*8, aArr + b*8, cArr + b*8);
    corr_kernel<<<512,256,0,stream>>>(colsum + b*HD_, Wot, cArr + b*8, corrB + b*C_);
    // U_b[:, z*512+d] = a[b,z] * (P~_z @ V_z)
    gemm256<<<dim3(13,2,8),512,0,stream>>>(S_b, Vt_b, Qf_b, NQ_, 512, NKP_,
        NKP_, NKP_, HD_, 8, 0, (long long)NQ_*NKP_, 0, (long long)512*NKP_, 0, 512,
        nullptr, 1.0f, aArr + b*8);
    if(!tierA){
      gemm_bt<1><<<dim3(25,4,1),256,0,stream>>>(Qf_b, Wot, out + (size_t)b*NQ_*C_,
          NQ_, HD_, HD_, HD_, C_,
          1, 0,0,0,0,0,0, bo, 1.0f, nullptr, corrB + b*C_, NQ_, C_);
    }
  }

  if(tierA){
    gemm_bt<1><<<dim3(98,4,1),256,0,stream>>>(QfU, Wot, out, B_*NQ_, HD_, HD_, HD_, C_,
        1, 0,0,0,0,0,0, bo, 1.0f, nullptr, corrB, NQ_, C_);
  }
}

// Round 7
// 1012.861 us; speedup vs baseline: 2.5289x; 1.1429x over previous
//
#include <hip/hip_runtime.h>
#include <hip/hip_bf16.h>
#include <math.h>

typedef unsigned short u16;
typedef __attribute__((ext_vector_type(4))) float f32x4;
typedef __attribute__((ext_vector_type(8))) __bf16 bf16x8;

#define B_    4
#define NQ_   3136
#define C_    512
#define HIMG  56
#define WIMG  56
#define HD_   4096
#define NK_   784
#define NKP_  832

static __device__ __forceinline__ float b2f(u16 u){
  union { unsigned int i; float f; } v; v.i = ((unsigned int)u)<<16; return v.f;
}
static __device__ __forceinline__ u16 f2b(float f){
  union { float f; unsigned int i; } v; v.f = f;
  unsigned int r = v.i + 0x7fffu + ((v.i>>16)&1u);
  return (u16)(r>>16);
}

#define GLD16(gsrc, ldst) __builtin_amdgcn_global_load_lds( \
    (const __attribute__((address_space(1))) void*)(gsrc), \
    (__attribute__((address_space(3))) void*)(ldst), 16, 0, 0)

// bijective XCD-aware block remap (m204): consecutive wg per XCD, y-fastest
static __device__ __forceinline__ void xcd_swz(int &bx, int &by, int &bz){
  const long nx = gridDim.x, ny = gridDim.y, nz = gridDim.z;
  const long l = blockIdx.x + nx*(blockIdx.y + ny*(long)blockIdx.z);
  const long n = nx*ny*nz;
  const long q8 = n>>3, r8 = n&7;
  const long xcd = l&7, idx = l>>3;
  const long wg = (xcd<r8 ? xcd*(q8+1) : r8*(q8+1) + (xcd-r8)*q8) + idx;
  by = (int)(wg % ny);
  bx = (int)((wg/ny) % nx);
  bz = (int)(wg/(nx*ny));
}

// ---------------------------------------------------------------------------
// 256x128 8-wave bf16 GEMM v3: 3-buffer rotation, stage-inside-phase,
// counted vmcnt(6), per-phase pre-MFMA barrier (lockstep), XOR LDS swizzle.
// C[m,n] = (sum_k A[m,k]*B[n,k] + bias1[n]) * hscale * scalePtr[z], bf16 out.
// A:(M,K) stride sA; B:(N,K) stride sB. BK=64. LDS 144 KiB:
//   A bufs 3 x 32 KiB @0, B bufs 3 x 16 KiB @96 KiB.
// Waves 4(M) x 2(N); wave tile 64x64; per k-half: af[4]+bf[4], 16 MFMA.
// Tile j (buf=j%3): vmcnt(6|0 last); barrier;
//   phase h in {0,1}: 8 ds_read(half h) ; 3 GLD16 of tile j+2 -> buf (j+2)%3
//                     (free: last read in tile j-1) ; barrier ;
//                     setprio(1) 16 MFMA setprio(0)
// Swizzle involution chunk^=(row&7) on pre-swizzled global src + read addr.
// Loads NOT masked (caller guarantees over-read slack); stores masked.
// Requires K%64==0, K>=192.
// ---------------------------------------------------------------------------
__global__ __launch_bounds__(512)
void gemm256(const u16* __restrict__ A, const u16* __restrict__ Bm, u16* __restrict__ Cm,
             int M, int Ncols, int K, int sA, int sB, int sC, int zdiv,
             long long zA1, long long zA2, long long zB1, long long zB2,
             long long zC1, long long zC2,
             const float* __restrict__ bias1, float hscale,
             const float* __restrict__ scalePtr)
{
  __shared__ u16 lds[73728];     // 144 KiB
  int bx, by, z;
  xcd_swz(bx, by, z);
  const int zq = z / zdiv, zr = z % zdiv;
  const u16* Ab = A  + (long long)zq*zA1 + (long long)zr*zA2;
  const u16* Bb = Bm + (long long)zq*zB1 + (long long)zr*zB2;
  const int m0 = bx*256, n0 = by*128;
  const int t = threadIdx.x, w = t>>6, lane = t&63;
  const int wm = w>>1, wn = w&1;             // 4 x 2 wave grid
  const int l15 = lane & 15;

  // staging source (pre-swizzled column: involution c ^= row&7)
  const int srow = t>>3;                                   // 0..63
  const int scol = (((t&7) ^ ((t>>3)&7)) << 3);            // elems
  const u16* aS = Ab + (long long)(m0 + srow)*sA + scol;
  const u16* bS = Bb + (long long)(n0 + srow)*sB + scol;
  const long long sA64 = (long long)64*sA, sB64 = (long long)64*sB;
  const int w512 = w*512;

  // stage halves: H0 = A rows {0,64,128}; H1 = A row 192 + B rows {0,64}
#define STAGE_H0(jt, buf) do{                                     \
    const u16* a0_ = aS + (long long)(jt)*64;                     \
    u16* la_ = lds + (buf)*16384 + w512;                          \
    GLD16(a0_,            la_);                                   \
    GLD16(a0_ +   sA64,   la_ + 4096);                            \
    GLD16(a0_ + 2*sA64,   la_ + 8192);                            \
  }while(0)
#define STAGE_H1(jt, buf) do{                                     \
    const u16* a0_ = aS + (long long)(jt)*64;                     \
    const u16* b0_ = bS + (long long)(jt)*64;                     \
    u16* la_ = lds + (buf)*16384 + w512;                          \
    u16* lb_ = lds + 49152 + (buf)*8192 + w512;                   \
    GLD16(a0_ + 3*sA64,   la_ + 12288);                           \
    GLD16(b0_,            lb_);                                   \
    GLD16(b0_ +   sB64,   lb_ + 4096);                            \
  }while(0)

  f32x4 acc[4][4];
#pragma unroll
  for(int i=0;i<4;i++)
#pragma unroll
    for(int j=0;j<4;j++) acc[i][j] = (f32x4)(0.0f);

  const char* ldsc = (const char*)lds;
  const int ck0 = (((lane>>4)     ^ (lane&7)) << 4);   // k-half 0 swizzled chunk
  const int ck1 = (((4+(lane>>4)) ^ (lane&7)) << 4);   // k-half 1
  const int aRowB = (wm*64 + l15) * 128;               // A row byte base
  const int bRowB = (wn*64 + l15) * 128;               // B row byte base

  const int T = K >> 6;
  STAGE_H0(0, 0); STAGE_H1(0, 0);
  STAGE_H0(1, 1); STAGE_H1(1, 1);

  int buf = 0;
  for(int j=0; j<T; j++){
    if(j == T-1) asm volatile("s_waitcnt vmcnt(0)" ::: "memory");
    else         asm volatile("s_waitcnt vmcnt(6)" ::: "memory");
    asm volatile("s_barrier" ::: "memory");   // tile j in LDS; buf (j+2)%3 free

    const int aBuf = buf*32768 + aRowB;
    const int bBuf = 98304 + buf*16384 + bRowB;
    const int nbuf = (buf+2 >= 3) ? buf-1 : buf+2;   // (j+2)%3
    // ---- phase 0 (k-half 0) ----
    {
      bf16x8 af[4], bf[4];
#pragma unroll
      for(int fr=0; fr<4; fr++) af[fr] = *(const bf16x8*)(ldsc + aBuf + fr*2048 + ck0);
#pragma unroll
      for(int fn=0; fn<4; fn++) bf[fn] = *(const bf16x8*)(ldsc + bBuf + fn*2048 + ck0);
      if(j+2 < T) STAGE_H0(j+2, nbuf);
      asm volatile("s_barrier" ::: "memory");
      __builtin_amdgcn_s_setprio(1);
#pragma unroll
      for(int fr=0; fr<4; fr++)
#pragma unroll
        for(int fn=0; fn<4; fn++)
          acc[fr][fn] = __builtin_amdgcn_mfma_f32_16x16x32_bf16(af[fr], bf[fn], acc[fr][fn], 0,0,0);
      __builtin_amdgcn_s_setprio(0);
    }
    // ---- phase 1 (k-half 1) ----
    {
      bf16x8 af[4], bf[4];
#pragma unroll
      for(int fr=0; fr<4; fr++) af[fr] = *(const bf16x8*)(ldsc + aBuf + fr*2048 + ck1);
#pragma unroll
      for(int fn=0; fn<4; fn++) bf[fn] = *(const bf16x8*)(ldsc + bBuf + fn*2048 + ck1);
      if(j+2 < T) STAGE_H1(j+2, nbuf);
      asm volatile("s_barrier" ::: "memory");
      __builtin_amdgcn_s_setprio(1);
#pragma unroll
      for(int fr=0; fr<4; fr++)
#pragma unroll
        for(int fn=0; fn<4; fn++)
          acc[fr][fn] = __builtin_amdgcn_mfma_f32_16x16x32_bf16(af[fr], bf[fn], acc[fr][fn], 0,0,0);
      __builtin_amdgcn_s_setprio(0);
    }
    buf = (buf+1 >= 3) ? 0 : buf+1;
  }
#undef STAGE_H0
#undef STAGE_H1

  const float dsc = scalePtr ? scalePtr[z] : 1.0f;
  const long long cBase = (long long)zq*zC1 + (long long)zr*zC2;
  const int r4 = (lane>>4)*4;
#pragma unroll
  for(int mf=0; mf<4; mf++){
    const int row0 = m0 + wm*64 + mf*16 + r4;
#pragma unroll
    for(int nf=0; nf<4; nf++){
      const int col = n0 + wn*64 + nf*16 + l15;
      if(col < Ncols){
#pragma unroll
        for(int r=0;r<4;r++){
          const int row = row0 + r;
          if(row < M){
            float v = acc[mf][nf][r];
            if(bias1) v += bias1[col];
            Cm[cBase + (long long)row*sC + col] = f2b(v * hscale * dsc);
          }
        }
      }
    }
  }
}

// ---------------------------------------------------------------------------
// 128x128 GEMM kept for out-proj (K=4096 regime), now with XCD swizzle
// ---------------------------------------------------------------------------
template<int OUT_F32>
__global__ __launch_bounds__(256)
void gemm_bt(const u16* __restrict__ A, const u16* __restrict__ Bm, void* __restrict__ Cm,
             int M, int K, int sA, int sB, int sC, int zdiv,
             long long zA1, long long zA2, long long zB1, long long zB2,
             long long zC1, long long zC2,
             const float* __restrict__ bias1, float hscale,
             const float* __restrict__ scalePtr,
             const float* __restrict__ bias2, int rowsPerB, int b2s)
{
  __shared__ u16 lA[128*32];
  __shared__ u16 lB[128*32];
  int bx, by, z;
  xcd_swz(bx, by, z);
  const int zq = z / zdiv, zr = z % zdiv;
  const u16* Ab = A  + (long long)zq*zA1 + (long long)zr*zA2;
  const u16* Bb = Bm + (long long)zq*zB1 + (long long)zr*zB2;
  const int m0 = bx*128, n0 = by*128;
  const int t = threadIdx.x, wave = t>>6, lane = t&63;
  const int wm = (wave>>1)*64, wn = (wave&1)*64;
  const int lrow = t>>2, lcol = (t&3)*8;

  const u16* aSrc = Ab + (long long)(m0+lrow)*sA + lcol;
  const u16* bSrc = Bb + (long long)(n0+lrow)*sB + lcol;
  u16* lAw = lA + wave*512;
  u16* lBw = lB + wave*512;

  f32x4 acc[4][4];
#pragma unroll
  for(int i=0;i<4;i++)
#pragma unroll
    for(int j=0;j<4;j++) acc[i][j] = (f32x4)(0.0f);

  const int l16 = lane & 15, lk8 = (lane>>4)*8;

  for(int kk=0; kk<K; kk+=32){
    GLD16(aSrc,                    lAw);
    GLD16(aSrc + (long long)64*sA, lAw + 64*32);
    GLD16(bSrc,                    lBw);
    GLD16(bSrc + (long long)64*sB, lBw + 64*32);
    aSrc += 32; bSrc += 32;
    __syncthreads();
    bf16x8 af[4], bfr[4];
#pragma unroll
    for(int i=0;i<4;i++){
      af[i]  = *(const bf16x8*)(lA + (wm + i*16 + l16)*32 + lk8);
      bfr[i] = *(const bf16x8*)(lB + (wn + i*16 + l16)*32 + lk8);
    }
#pragma unroll
    for(int i=0;i<4;i++)
#pragma unroll
      for(int j=0;j<4;j++)
        acc[i][j] = __builtin_amdgcn_mfma_f32_16x16x32_bf16(af[i], bfr[j], acc[i][j], 0,0,0);
    __syncthreads();
  }

  const float dsc = scalePtr ? scalePtr[z] : 1.0f;
  const long long cBase = (long long)zq*zC1 + (long long)zr*zC2;
  const int rbase = (lane>>4)*4;
#pragma unroll
  for(int i=0;i<4;i++){
#pragma unroll
    for(int j=0;j<4;j++){
#pragma unroll
      for(int r=0;r<4;r++){
        const int row = m0 + wm + i*16 + rbase + r;
        const int col = n0 + wn + j*16 + l16;
        if(row < M){
          float v = acc[i][j][r];
          if(bias1) v += bias1[col];
          v *= hscale * dsc;
          if(bias2) v += bias2[(row/rowsPerB)*b2s + col];
          if(OUT_F32) ((float*)Cm)[cBase + (long long)row*sC + col] = v;
          else        ((u16*) Cm)[cBase + (long long)row*sC + col] = f2b(v);
        }
      }
    }
  }
}

// f32 (K,N) weight -> bf16 (N,K) transpose
__global__ __launch_bounds__(256)
void wt_kernel(const float* __restrict__ W, u16* __restrict__ Wt, int K, int N){
  __shared__ float tile[32][33];
  const int n0 = blockIdx.x*32, k0 = blockIdx.y*32;
  const int t = threadIdx.x, tr = t>>5, tc = t&31;
#pragma unroll
  for(int i=0;i<4;i++)
    tile[tr+i*8][tc] = W[(long long)(k0+tr+i*8)*N + n0+tc];
  __syncthreads();
#pragma unroll
  for(int i=0;i<4;i++)
    Wt[(long long)(n0+tr+i*8)*K + k0+tc] = f2b(tile[tc][tr+i*8]);
}

__global__ __launch_bounds__(256)
void cvt_bf16(const float* __restrict__ in, u16* __restrict__ outp, long long n){
  long long i = ((long long)blockIdx.x*256 + threadIdx.x)*4;
  if(i+3 < n){
    float4 v = *(const float4*)(in+i);
    ushort4 o; o.x=f2b(v.x); o.y=f2b(v.y); o.z=f2b(v.z); o.w=f2b(v.w);
    *(ushort4*)(outp+i) = o;
  }
}

// depthwise 3x3 stride-2 SAME conv (pad lo=0,hi=1) + bias + LayerNorm -> bf16
__global__ __launch_bounds__(256)
void conv_ln(const float* __restrict__ q, const float* __restrict__ ker,
             const float* __restrict__ cbias, const float* __restrict__ gamma,
             const float* __restrict__ beta, u16* __restrict__ xo)
{
  const int p = blockIdx.x;
  const int b = p / 784, pix = p % 784;
  const int oy = pix / 28, ox = pix % 28;
  const int t = threadIdx.x;
  __shared__ float red[256];
  float v[2];
#pragma unroll
  for(int e=0;e<2;e++){
    const int c = t + e*256;
    float acc = cbias[c];
    for(int ky=0;ky<3;ky++){
      const int y = oy*2 + ky;
      if(y >= HIMG) continue;
      for(int kx=0;kx<3;kx++){
        const int x = ox*2 + kx;
        if(x >= WIMG) continue;
        acc += q[(((long long)b*HIMG + y)*WIMG + x)*C_ + c] * ker[(ky*3+kx)*C_ + c];
      }
    }
    v[e] = acc;
  }
  red[t]=v[0]+v[1]; __syncthreads();
  for(int st=128; st>0; st>>=1){ if(t<st) red[t]+=red[t+st]; __syncthreads(); }
  const float mu = red[0] * (1.0f/C_);
  __syncthreads();
  const float d0=v[0]-mu, d1=v[1]-mu;
  red[t]=d0*d0+d1*d1; __syncthreads();
  for(int st=128; st>0; st>>=1){ if(t<st) red[t]+=red[t+st]; __syncthreads(); }
  const float rs = rsqrtf(red[0]*(1.0f/C_) + 1e-3f);
  const long long ob = (long long)p*C_;
#pragma unroll
  for(int e=0;e<2;e++){
    const int c = t+e*256;
    xo[ob+c] = f2b((v[e]-mu)*rs*gamma[c] + beta[c]);
  }
}

// per-batch: V part of KV_b (784 x 4096, row stride sV) -> Vt_b (4096,832), k zero-padded
__global__ __launch_bounds__(256)
void vt_kernel(const u16* __restrict__ Vf_b, u16* __restrict__ Vt_b, int sV){
  __shared__ u16 tile[32][33];
  const int k0 = blockIdx.x*32, d0 = blockIdx.y*32;
  const int t = threadIdx.x, tr = t>>5, tc = t&31;
#pragma unroll
  for(int i=0;i<4;i++){
    const int k = k0+tr+i*8;
    tile[tr+i*8][tc] = (k < NK_) ? Vf_b[(long long)k*sV + d0+tc] : (u16)0;
  }
  __syncthreads();
#pragma unroll
  for(int i=0;i<4;i++)
    Vt_b[(long long)(d0+tr+i*8)*NKP_ + k0+tc] = tile[tc][tr+i*8];
}

// ---------------------------------------------------------------------------
// Wave-parallel mix+softmax: one block (512 thr = 8 waves) per q-row.
// Unique-slot partial sums (no hot atomics). Zeroes pad cols 784..831.
// ---------------------------------------------------------------------------
__global__ __launch_bounds__(512)
void mix_softmax(u16* __restrict__ S_b, const float* __restrict__ tw,
                 float* __restrict__ partial_b)
{
  const int qi = blockIdx.x;
  const int t = threadIdx.x;
  const int wave = t >> 6, lane = t & 63;
  __shared__ float sv[8*NK_];
  const long long rowstr = (long long)NQ_*NKP_;
  const long long base = (long long)qi*NKP_;

  for(int idx = t; idx < 8*196; idx += 512){
    const int h = idx / 196, c4 = idx % 196;
    ushort4 u4 = *(const ushort4*)(S_b + base + h*rowstr + c4*4);
    float* d = sv + h*NK_ + c4*4;
    d[0]=b2f(u4.x); d[1]=b2f(u4.y); d[2]=b2f(u4.z); d[3]=b2f(u4.w);
  }
  __syncthreads();

  const int g = wave;
  float wgt[8];
#pragma unroll
  for(int h=0;h<8;h++) wgt[h] = tw[h*8+g];

  float xs[13];
  float lmax = -1e30f;
#pragma unroll
  for(int j=0;j<13;j++){
    const int k = j*64 + lane;
    if(k < NK_){
      float x = 0.f;
#pragma unroll
      for(int h=0;h<8;h++) x += wgt[h]*sv[h*NK_+k];
      xs[j] = x;
      lmax = fmaxf(lmax, x);
    } else xs[j] = -1e30f;
  }
#pragma unroll
  for(int off=32; off>=1; off>>=1) lmax = fmaxf(lmax, __shfl_xor(lmax, off));

  float lsum = 0.f;
#pragma unroll
  for(int j=0;j<13;j++){
    const int k = j*64 + lane;
    if(k < NK_){
      const float e = __expf(xs[j] - lmax);
      xs[j] = e; lsum += e;
    }
  }
#pragma unroll
  for(int off=32; off>=1; off>>=1) lsum += __shfl_xor(lsum, off);
  const float inv = 1.0f/lsum;

  u16* dst = S_b + base + g*rowstr;
  float lss = 0.f;
#pragma unroll
  for(int j=0;j<13;j++){
    const int k = j*64 + lane;
    if(k < NK_){
      const float dev = xs[j]*inv - (1.0f/NK_);
      dst[k] = f2b(dev);
      lss += dev*dev;
    }
  }
  for(int k = NK_ + lane; k < NKP_; k += 64) dst[k] = 0;
#pragma unroll
  for(int off=32; off>=1; off>>=1) lss += __shfl_xor(lss, off);
  if(lane==0) partial_b[g*NQ_ + qi] = lss;
}

__global__ __launch_bounds__(256)
void colsum_v(const u16* __restrict__ Vf_b, float* __restrict__ cs_b, int sV){
  const int hd = blockIdx.x*256 + threadIdx.x;
  const u16* p = Vf_b + hd;
  float s=0.f;
  for(int k=0;k<NK_;k++) s += b2f(p[(long long)k*sV]);
  cs_b[hd]=s;
}

__global__ __launch_bounds__(256)
void finalize_stats(const float* __restrict__ partial_b, const float* __restrict__ bng_b,
                    const float* __restrict__ bnb_b, float* __restrict__ a_b,
                    float* __restrict__ c_b){
  const int g = blockIdx.x;
  const int t = threadIdx.x;
  __shared__ float red[4];
  float s = 0.f;
  for(int i=t; i<NQ_; i+=256) s += partial_b[g*NQ_ + i];
#pragma unroll
  for(int off=32; off>=1; off>>=1) s += __shfl_xor(s, off);
  if((t&63)==0) red[t>>6] = s;
  __syncthreads();
  if(t==0){
    const float tot = red[0]+red[1]+red[2]+red[3];
    const float s2 = tot * (1.0f/((float)NQ_*(float)NK_));
    a_b[g] = bng_b[g]*rsqrtf(s2 + 1e-3f);
    c_b[g] = bnb_b[g];
  }
}

__global__ __launch_bounds__(256)
void corr_kernel(const float* __restrict__ cs_b, const u16* __restrict__ Wot,
                 const float* __restrict__ c_b, float* __restrict__ corr_b){
  const int n = blockIdx.x, t = threadIdx.x;
  __shared__ float red[256];
  float s = 0.f;
  for(int hd=t; hd<HD_; hd+=256)
    s += c_b[hd>>9] * cs_b[hd] * b2f(Wot[(long long)n*HD_+hd]);
  red[t]=s; __syncthreads();
  for(int st=128; st>0; st>>=1){ if(t<st) red[t]+=red[t+st]; __syncthreads(); }
  if(t==0) corr_b[n]=red[0];
}

// ---------------------------------------------------------------------------
extern "C" void kernel_launch(void* const* d_in, const int* in_sizes, int n_in,
                              void* d_out, int out_size, void* d_ws, size_t ws_size,
                              hipStream_t stream)
{
  (void)in_sizes; (void)n_in; (void)out_size;
  const float* queries = (const float*)d_in[0];
  const float* Wq  = (const float*)d_in[3];
  const float* bq  = (const float*)d_in[4];
  const float* Wk  = (const float*)d_in[5];
  const float* bk  = (const float*)d_in[6];
  const float* Wv  = (const float*)d_in[7];
  const float* bv  = (const float*)d_in[8];
  const float* Wo  = (const float*)d_in[9];
  const float* bo  = (const float*)d_in[10];
  const float* srk = (const float*)d_in[11];
  const float* srb = (const float*)d_in[12];
  const float* lng = (const float*)d_in[13];
  const float* lnb = (const float*)d_in[14];
  const float* tw  = (const float*)d_in[15];
  const float* bng = (const float*)d_in[17];
  const float* bnb = (const float*)d_in[18];
  float* out = (float*)d_out;
  const float QSC = 0.04419417382415922f;   // 1/sqrt(512)

  char* w = (char*)d_ws;
  size_t off = 0;
  auto alloc = [&](size_t bytes)->char*{
    char* p = w + off; off += (bytes + 255) & ~(size_t)255; return p;
  };

  const bool tierA = (ws_size >= (size_t)210*1024*1024);

  u16* Wqt = (u16*)alloc((size_t)HD_*C_*2);
  u16* Wkt = (u16*)alloc((size_t)HD_*C_*2);   // Wvt follows contiguously
  u16* Wvt = (u16*)alloc((size_t)HD_*C_*2);
  u16* Wot = (u16*)alloc((size_t)C_*HD_*2);
  u16* x   = (u16*)alloc((size_t)B_*NK_*C_*2 + 262144);     // +256K over-read pad
  float* bkv = (float*)alloc((size_t)2*HD_*4);              // bk || bv
  u16* Qin;
  u16* QfU;
  if(tierA){
    Qin = (u16*)alloc((size_t)B_*NQ_*C_*2);
    QfU = (u16*)alloc((size_t)B_*NQ_*HD_*2);
  } else {
    Qin = (u16*)alloc((size_t)NQ_*C_*2 + 262144);
    QfU = (u16*)alloc((size_t)NQ_*HD_*2);
  }
  u16* KV_b = (u16*)alloc((size_t)NK_*2*HD_*2 + 4194304);  // +4M: score B over-read (240 rows)
  u16* Vt_b = (u16*)alloc((size_t)HD_*NKP_*2);
  u16* S_b  = (u16*)alloc((size_t)8*NQ_*NKP_*2 + 524288);   // +512K PV A over-read pad
  float* colsum  = (float*)alloc((size_t)B_*HD_*4);
  float* partial = (float*)alloc((size_t)8*NQ_*4);
  float* aArr    = (float*)alloc(256);
  float* cArr    = (float*)alloc(256);
  float* corrB   = (float*)alloc((size_t)B_*C_*4);

  // ---- weight prep + conv+LN ----
  wt_kernel<<<dim3(128,16), 256, 0, stream>>>(Wq, Wqt, 512, 4096);
  wt_kernel<<<dim3(128,16), 256, 0, stream>>>(Wk, Wkt, 512, 4096);
  wt_kernel<<<dim3(128,16), 256, 0, stream>>>(Wv, Wvt, 512, 4096);
  wt_kernel<<<dim3(16,128), 256, 0, stream>>>(Wo, Wot, 4096, 512);
  conv_ln<<<B_*NK_, 256, 0, stream>>>(queries, srk, srb, lng, lnb, x);
  hipMemcpyAsync(bkv,      bk, HD_*4, hipMemcpyDeviceToDevice, stream);
  hipMemcpyAsync(bkv+HD_,  bv, HD_*4, hipMemcpyDeviceToDevice, stream);

  if(tierA){
    cvt_bf16<<<6272, 256, 0, stream>>>(queries, Qin, (long long)B_*NQ_*C_);
    // Qf = (queries@Wq + bq)/sqrt(512)
    gemm256<<<dim3(49,32,1),512,0,stream>>>(Qin, Wqt, QfU, B_*NQ_, 4096, 512,
        512, 512, HD_, 1, 0,0,0,0,0,0, bq, QSC, nullptr);
  }

  for(int b=0; b<B_; b++){
    u16* Qf_b = tierA ? (QfU + (size_t)b*NQ_*HD_) : QfU;
    if(!tierA){
      cvt_bf16<<<1568, 256, 0, stream>>>(queries + (size_t)b*NQ_*C_, Qin, (long long)NQ_*C_);
      gemm256<<<dim3(13,32,1),512,0,stream>>>(Qin, Wqt, Qf_b, NQ_, 4096, 512,
          512, 512, HD_, 1, 0,0,0,0,0,0, bq, QSC, nullptr);
    }
    const u16* x_b = x + (size_t)b*NK_*C_;
    // combined K|V projection: B spans Wkt..Wvt (adjacent, 8192 rows)
    gemm256<<<dim3(4,64,1),512,0,stream>>>(x_b, Wkt, KV_b, NK_, 2*HD_, 512,
        512, 512, 2*HD_, 1, 0,0,0,0,0,0, bkv, 1.0f, nullptr);
    vt_kernel<<<dim3(26,128),256,0,stream>>>(KV_b + HD_, Vt_b, 2*HD_);
    colsum_v<<<16,256,0,stream>>>(KV_b + HD_, colsum + b*HD_, 2*HD_);
    // per-head scores: S_b[z] = Qf_b[:, z*512:+512] @ K_b[:, z*512:+512]^T
    gemm256<<<dim3(13,7,8),512,0,stream>>>(Qf_b, KV_b, S_b, NQ_, NKP_, 512,
        HD_, 2*HD_, NKP_, 8, 0, 512, 0, 512, 0, (long long)NQ_*NKP_,
        nullptr, 1.0f, nullptr);
    mix_softmax<<<NQ_, 512, 0, stream>>>(S_b, tw, partial);
    finalize_stats<<<8,256,0,stream>>>(partial, bng + b*8, bnb + b*8, aArr + b*8, cArr + b*8);
    corr_kernel<<<512,256,0,stream>>>(colsum + b*HD_, Wot, cArr + b*8, corrB + b*C_);
    // U_b[:, z*512+d] = a[b,z] * (P~_z @ V_z)
    gemm256<<<dim3(13,4,8),512,0,stream>>>(S_b, Vt_b, Qf_b, NQ_, 512, NKP_,
        NKP_, NKP_, HD_, 8, 0, (long long)NQ_*NKP_, 0, (long long)512*NKP_, 0, 512,
        nullptr, 1.0f, aArr + b*8);
    if(!tierA){
      gemm_bt<1><<<dim3(25,4,1),256,0,stream>>>(Qf_b, Wot, out + (size_t)b*NQ_*C_,
          NQ_, HD_, HD_, HD_, C_,
          1, 0,0,0,0,0,0, bo, 1.0f, nullptr, corrB + b*C_, NQ_, C_);
    }
  }

  if(tierA){
    gemm_bt<1><<<dim3(98,4,1),256,0,stream>>>(QfU, Wot, out, B_*NQ_, HD_, HD_, HD_, C_,
        1, 0,0,0,0,0,0, bo, 1.0f, nullptr, corrB, NQ_, C_);
  }
}

// Round 8
// 1007.604 us; speedup vs baseline: 2.5421x; 1.0052x over previous
//
#include <hip/hip_runtime.h>
#include <hip/hip_bf16.h>
#include <math.h>

typedef unsigned short u16;
typedef __attribute__((ext_vector_type(4))) float f32x4;
typedef __attribute__((ext_vector_type(8))) __bf16 bf16x8;

#define B_    4
#define NQ_   3136
#define C_    512
#define HIMG  56
#define WIMG  56
#define HD_   4096
#define NK_   784
#define NKP_  832

static __device__ __forceinline__ float b2f(u16 u){
  union { unsigned int i; float f; } v; v.i = ((unsigned int)u)<<16; return v.f;
}
static __device__ __forceinline__ u16 f2b(float f){
  union { float f; unsigned int i; } v; v.f = f;
  unsigned int r = v.i + 0x7fffu + ((v.i>>16)&1u);
  return (u16)(r>>16);
}

#define GLD16(gsrc, ldst) __builtin_amdgcn_global_load_lds( \
    (const __attribute__((address_space(1))) void*)(gsrc), \
    (__attribute__((address_space(3))) void*)(ldst), 16, 0, 0)

// bijective XCD-aware block remap (m204): consecutive wg per XCD, y-fastest
static __device__ __forceinline__ void xcd_swz(int &bx, int &by, int &bz){
  const long nx = gridDim.x, ny = gridDim.y, nz = gridDim.z;
  const long l = blockIdx.x + nx*(blockIdx.y + ny*(long)blockIdx.z);
  const long n = nx*ny*nz;
  const long q8 = n>>3, r8 = n&7;
  const long xcd = l&7, idx = l>>3;
  const long wg = (xcd<r8 ? xcd*(q8+1) : r8*(q8+1) + (xcd-r8)*q8) + idx;
  by = (int)(wg % ny);
  bx = (int)((wg/ny) % nx);
  bz = (int)(wg/(nx*ny));
}

// ---------------------------------------------------------------------------
// 128x128 4-wave bf16 GEMM v4: 64 KiB LDS -> 2 blocks/CU (inter-block overlap
// replaces the barrier-locked single-block schedule of v3).
// C[m,n] = (sum_k A[m,k]*B[n,k] + bias1[n]) * hscale * scalePtr[z] (+bias2),
// bf16 or f32 out. A:(M,K) stride sA; B:(N,K) stride sB. BK=64.
// LDS: A bufs 2x16K @0, B bufs 2x16K @32K (bytes).
// Waves 2(M)x2(N); wave tile 64x64; per k-half af[4]+bf[4], 16 MFMA.
// Tile j (buf bj=j&1):
//   s_waitcnt vmcnt(8|0 last); s_barrier      -> tile j landed (all waves)
//   {16 ds_read + 32 MFMA, both k-halves; setprio(1) around MFMA}
//   s_barrier                                  -> all reads of buf bj done
//   STAGE(j+2 -> bj)   (8 GLD16; in flight across next barrier, counted)
// XOR swizzle involution chunk^=(row&7) on pre-swizzled global source column
// and ds_read chunk (measured conflict-free, r5-r7).
// Loads NOT masked (caller guarantees over-read slack); stores masked.
// Requires K%64==0, K>=128.
// ---------------------------------------------------------------------------
template<int OUT_F32>
__global__ __launch_bounds__(256)
void gemm128(const u16* __restrict__ A, const u16* __restrict__ Bm, void* __restrict__ Cm,
             int M, int Ncols, int K, int sA, int sB, int sC, int zdiv,
             long long zA1, long long zA2, long long zB1, long long zB2,
             long long zC1, long long zC2,
             const float* __restrict__ bias1, float hscale,
             const float* __restrict__ scalePtr,
             const float* __restrict__ bias2, int rowsPerB, int b2s)
{
  __shared__ u16 lds[32768];     // 64 KiB
  int bx, by, z;
  xcd_swz(bx, by, z);
  const int zq = z / zdiv, zr = z % zdiv;
  const u16* Ab = A  + (long long)zq*zA1 + (long long)zr*zA2;
  const u16* Bb = Bm + (long long)zq*zB1 + (long long)zr*zB2;
  const int m0 = bx*128, n0 = by*128;
  const int t = threadIdx.x, w = t>>6, lane = t&63;
  const int wm = w>>1, wn = w&1;             // 2 x 2 wave grid
  const int l15 = lane & 15;

  // staging: 8 threads/row, 32 rows/inst; pre-swizzled source column
  const int srow = t>>3;                                   // 0..31
  const int scol = (((t&7) ^ (srow&7)) << 3);              // elems
  const u16* aS = Ab + (long long)(m0 + srow)*sA + scol;
  const u16* bS = Bb + (long long)(n0 + srow)*sB + scol;
  const long long sA32 = (long long)32*sA, sB32 = (long long)32*sB;
  const int w512 = w*512;                                  // u16: wave base 1 KB

#define STAGE(jt, buf) do{                                        \
    const u16* a0_ = aS + (long long)(jt)*64;                     \
    const u16* b0_ = bS + (long long)(jt)*64;                     \
    u16* la_ = lds + (buf)*8192 + w512;                           \
    u16* lb_ = lds + 16384 + (buf)*8192 + w512;                   \
    GLD16(a0_,            la_);                                   \
    GLD16(a0_ +   sA32,   la_ + 2048);                            \
    GLD16(a0_ + 2*sA32,   la_ + 4096);                            \
    GLD16(a0_ + 3*sA32,   la_ + 6144);                            \
    GLD16(b0_,            lb_);                                   \
    GLD16(b0_ +   sB32,   lb_ + 2048);                            \
    GLD16(b0_ + 2*sB32,   lb_ + 4096);                            \
    GLD16(b0_ + 3*sB32,   lb_ + 6144);                            \
  }while(0)

  f32x4 acc[4][4];
#pragma unroll
  for(int i=0;i<4;i++)
#pragma unroll
    for(int j=0;j<4;j++) acc[i][j] = (f32x4)(0.0f);

  const char* ldsc = (const char*)lds;
  const int ck0 = (((lane>>4)     ^ (lane&7)) << 4);   // k-half 0 chunk
  const int ck1 = (((4+(lane>>4)) ^ (lane&7)) << 4);   // k-half 1 chunk
  const int aRowB = (wm*64 + l15) * 128;               // A row byte base
  const int bRowB = (wn*64 + l15) * 128;               // B row byte base

  const int T = K >> 6;
  STAGE(0, 0);
  STAGE(1, 1);

  for(int j=0; j<T; j++){
    const int bj = j & 1;
    if(j == T-1) asm volatile("s_waitcnt vmcnt(0)" ::: "memory");
    else         asm volatile("s_waitcnt vmcnt(8)" ::: "memory");
    asm volatile("s_barrier" ::: "memory");   // tile j visible to all waves

    const int aBuf = bj*16384 + aRowB;
    const int bBuf = 32768 + bj*16384 + bRowB;
    {
      bf16x8 af[4], bf[4];
#pragma unroll
      for(int fr=0; fr<4; fr++) af[fr] = *(const bf16x8*)(ldsc + aBuf + fr*2048 + ck0);
#pragma unroll
      for(int fn=0; fn<4; fn++) bf[fn] = *(const bf16x8*)(ldsc + bBuf + fn*2048 + ck0);
      __builtin_amdgcn_s_setprio(1);
#pragma unroll
      for(int fr=0; fr<4; fr++)
#pragma unroll
        for(int fn=0; fn<4; fn++)
          acc[fr][fn] = __builtin_amdgcn_mfma_f32_16x16x32_bf16(af[fr], bf[fn], acc[fr][fn], 0,0,0);
      __builtin_amdgcn_s_setprio(0);
    }
    {
      bf16x8 af[4], bf[4];
#pragma unroll
      for(int fr=0; fr<4; fr++) af[fr] = *(const bf16x8*)(ldsc + aBuf + fr*2048 + ck1);
#pragma unroll
      for(int fn=0; fn<4; fn++) bf[fn] = *(const bf16x8*)(ldsc + bBuf + fn*2048 + ck1);
      __builtin_amdgcn_s_setprio(1);
#pragma unroll
      for(int fr=0; fr<4; fr++)
#pragma unroll
        for(int fn=0; fn<4; fn++)
          acc[fr][fn] = __builtin_amdgcn_mfma_f32_16x16x32_bf16(af[fr], bf[fn], acc[fr][fn], 0,0,0);
      __builtin_amdgcn_s_setprio(0);
    }
    asm volatile("s_barrier" ::: "memory");  // all reads of buffer bj done
    if(j+2 < T) STAGE(j+2, bj);
  }
#undef STAGE

  const float dsc = scalePtr ? scalePtr[z] : 1.0f;
  const long long cBase = (long long)zq*zC1 + (long long)zr*zC2;
  const int r4 = (lane>>4)*4;
#pragma unroll
  for(int mf=0; mf<4; mf++){
    const int row0 = m0 + wm*64 + mf*16 + r4;
#pragma unroll
    for(int nf=0; nf<4; nf++){
      const int col = n0 + wn*64 + nf*16 + l15;
      if(col < Ncols){
#pragma unroll
        for(int r=0;r<4;r++){
          const int row = row0 + r;
          if(row < M){
            float v = acc[mf][nf][r];
            if(bias1) v += bias1[col];
            v *= hscale * dsc;
            if(bias2) v += bias2[(row/rowsPerB)*b2s + col];
            if(OUT_F32) ((float*)Cm)[cBase + (long long)row*sC + col] = v;
            else        ((u16*) Cm)[cBase + (long long)row*sC + col] = f2b(v);
          }
        }
      }
    }
  }
}

// f32 (K,N) weight -> bf16 (N,K) transpose
__global__ __launch_bounds__(256)
void wt_kernel(const float* __restrict__ W, u16* __restrict__ Wt, int K, int N){
  __shared__ float tile[32][33];
  const int n0 = blockIdx.x*32, k0 = blockIdx.y*32;
  const int t = threadIdx.x, tr = t>>5, tc = t&31;
#pragma unroll
  for(int i=0;i<4;i++)
    tile[tr+i*8][tc] = W[(long long)(k0+tr+i*8)*N + n0+tc];
  __syncthreads();
#pragma unroll
  for(int i=0;i<4;i++)
    Wt[(long long)(n0+tr+i*8)*K + k0+tc] = f2b(tile[tc][tr+i*8]);
}

__global__ __launch_bounds__(256)
void cvt_bf16(const float* __restrict__ in, u16* __restrict__ outp, long long n){
  long long i = ((long long)blockIdx.x*256 + threadIdx.x)*4;
  if(i+3 < n){
    float4 v = *(const float4*)(in+i);
    ushort4 o; o.x=f2b(v.x); o.y=f2b(v.y); o.z=f2b(v.z); o.w=f2b(v.w);
    *(ushort4*)(outp+i) = o;
  }
}

// depthwise 3x3 stride-2 SAME conv (pad lo=0,hi=1) + bias + LayerNorm -> bf16
__global__ __launch_bounds__(256)
void conv_ln(const float* __restrict__ q, const float* __restrict__ ker,
             const float* __restrict__ cbias, const float* __restrict__ gamma,
             const float* __restrict__ beta, u16* __restrict__ xo)
{
  const int p = blockIdx.x;
  const int b = p / 784, pix = p % 784;
  const int oy = pix / 28, ox = pix % 28;
  const int t = threadIdx.x;
  __shared__ float red[256];
  float v[2];
#pragma unroll
  for(int e=0;e<2;e++){
    const int c = t + e*256;
    float acc = cbias[c];
    for(int ky=0;ky<3;ky++){
      const int y = oy*2 + ky;
      if(y >= HIMG) continue;
      for(int kx=0;kx<3;kx++){
        const int x = ox*2 + kx;
        if(x >= WIMG) continue;
        acc += q[(((long long)b*HIMG + y)*WIMG + x)*C_ + c] * ker[(ky*3+kx)*C_ + c];
      }
    }
    v[e] = acc;
  }
  red[t]=v[0]+v[1]; __syncthreads();
  for(int st=128; st>0; st>>=1){ if(t<st) red[t]+=red[t+st]; __syncthreads(); }
  const float mu = red[0] * (1.0f/C_);
  __syncthreads();
  const float d0=v[0]-mu, d1=v[1]-mu;
  red[t]=d0*d0+d1*d1; __syncthreads();
  for(int st=128; st>0; st>>=1){ if(t<st) red[t]+=red[t+st]; __syncthreads(); }
  const float rs = rsqrtf(red[0]*(1.0f/C_) + 1e-3f);
  const long long ob = (long long)p*C_;
#pragma unroll
  for(int e=0;e<2;e++){
    const int c = t+e*256;
    xo[ob+c] = f2b((v[e]-mu)*rs*gamma[c] + beta[c]);
  }
}

// per-batch: V part of KV_b (784 x 4096, row stride sV) -> Vt_b (4096,832), k zero-padded
__global__ __launch_bounds__(256)
void vt_kernel(const u16* __restrict__ Vf_b, u16* __restrict__ Vt_b, int sV){
  __shared__ u16 tile[32][33];
  const int k0 = blockIdx.x*32, d0 = blockIdx.y*32;
  const int t = threadIdx.x, tr = t>>5, tc = t&31;
#pragma unroll
  for(int i=0;i<4;i++){
    const int k = k0+tr+i*8;
    tile[tr+i*8][tc] = (k < NK_) ? Vf_b[(long long)k*sV + d0+tc] : (u16)0;
  }
  __syncthreads();
#pragma unroll
  for(int i=0;i<4;i++)
    Vt_b[(long long)(d0+tr+i*8)*NKP_ + k0+tc] = tile[tc][tr+i*8];
}

// ---------------------------------------------------------------------------
// Wave-parallel mix+softmax: one block (512 thr = 8 waves) per q-row.
// Unique-slot partial sums (no hot atomics). Zeroes pad cols 784..831.
// ---------------------------------------------------------------------------
__global__ __launch_bounds__(512)
void mix_softmax(u16* __restrict__ S_b, const float* __restrict__ tw,
                 float* __restrict__ partial_b)
{
  const int qi = blockIdx.x;
  const int t = threadIdx.x;
  const int wave = t >> 6, lane = t & 63;
  __shared__ float sv[8*NK_];
  const long long rowstr = (long long)NQ_*NKP_;
  const long long base = (long long)qi*NKP_;

  for(int idx = t; idx < 8*196; idx += 512){
    const int h = idx / 196, c4 = idx % 196;
    ushort4 u4 = *(const ushort4*)(S_b + base + h*rowstr + c4*4);
    float* d = sv + h*NK_ + c4*4;
    d[0]=b2f(u4.x); d[1]=b2f(u4.y); d[2]=b2f(u4.z); d[3]=b2f(u4.w);
  }
  __syncthreads();

  const int g = wave;
  float wgt[8];
#pragma unroll
  for(int h=0;h<8;h++) wgt[h] = tw[h*8+g];

  float xs[13];
  float lmax = -1e30f;
#pragma unroll
  for(int j=0;j<13;j++){
    const int k = j*64 + lane;
    if(k < NK_){
      float x = 0.f;
#pragma unroll
      for(int h=0;h<8;h++) x += wgt[h]*sv[h*NK_+k];
      xs[j] = x;
      lmax = fmaxf(lmax, x);
    } else xs[j] = -1e30f;
  }
#pragma unroll
  for(int off=32; off>=1; off>>=1) lmax = fmaxf(lmax, __shfl_xor(lmax, off));

  float lsum = 0.f;
#pragma unroll
  for(int j=0;j<13;j++){
    const int k = j*64 + lane;
    if(k < NK_){
      const float e = __expf(xs[j] - lmax);
      xs[j] = e; lsum += e;
    }
  }
#pragma unroll
  for(int off=32; off>=1; off>>=1) lsum += __shfl_xor(lsum, off);
  const float inv = 1.0f/lsum;

  u16* dst = S_b + base + g*rowstr;
  float lss = 0.f;
#pragma unroll
  for(int j=0;j<13;j++){
    const int k = j*64 + lane;
    if(k < NK_){
      const float dev = xs[j]*inv - (1.0f/NK_);
      dst[k] = f2b(dev);
      lss += dev*dev;
    }
  }
  for(int k = NK_ + lane; k < NKP_; k += 64) dst[k] = 0;
#pragma unroll
  for(int off=32; off>=1; off>>=1) lss += __shfl_xor(lss, off);
  if(lane==0) partial_b[g*NQ_ + qi] = lss;
}

__global__ __launch_bounds__(256)
void colsum_v(const u16* __restrict__ Vf_b, float* __restrict__ cs_b, int sV){
  const int hd = blockIdx.x*256 + threadIdx.x;
  const u16* p = Vf_b + hd;
  float s=0.f;
  for(int k=0;k<NK_;k++) s += b2f(p[(long long)k*sV]);
  cs_b[hd]=s;
}

__global__ __launch_bounds__(256)
void finalize_stats(const float* __restrict__ partial_b, const float* __restrict__ bng_b,
                    const float* __restrict__ bnb_b, float* __restrict__ a_b,
                    float* __restrict__ c_b){
  const int g = blockIdx.x;
  const int t = threadIdx.x;
  __shared__ float red[4];
  float s = 0.f;
  for(int i=t; i<NQ_; i+=256) s += partial_b[g*NQ_ + i];
#pragma unroll
  for(int off=32; off>=1; off>>=1) s += __shfl_xor(s, off);
  if((t&63)==0) red[t>>6] = s;
  __syncthreads();
  if(t==0){
    const float tot = red[0]+red[1]+red[2]+red[3];
    const float s2 = tot * (1.0f/((float)NQ_*(float)NK_));
    a_b[g] = bng_b[g]*rsqrtf(s2 + 1e-3f);
    c_b[g] = bnb_b[g];
  }
}

__global__ __launch_bounds__(256)
void corr_kernel(const float* __restrict__ cs_b, const u16* __restrict__ Wot,
                 const float* __restrict__ c_b, float* __restrict__ corr_b){
  const int n = blockIdx.x, t = threadIdx.x;
  __shared__ float red[256];
  float s = 0.f;
  for(int hd=t; hd<HD_; hd+=256)
    s += c_b[hd>>9] * cs_b[hd] * b2f(Wot[(long long)n*HD_+hd]);
  red[t]=s; __syncthreads();
  for(int st=128; st>0; st>>=1){ if(t<st) red[t]+=red[t+st]; __syncthreads(); }
  if(t==0) corr_b[n]=red[0];
}

// ---------------------------------------------------------------------------
extern "C" void kernel_launch(void* const* d_in, const int* in_sizes, int n_in,
                              void* d_out, int out_size, void* d_ws, size_t ws_size,
                              hipStream_t stream)
{
  (void)in_sizes; (void)n_in; (void)out_size;
  const float* queries = (const float*)d_in[0];
  const float* Wq  = (const float*)d_in[3];
  const float* bq  = (const float*)d_in[4];
  const float* Wk  = (const float*)d_in[5];
  const float* bk  = (const float*)d_in[6];
  const float* Wv  = (const float*)d_in[7];
  const float* bv  = (const float*)d_in[8];
  const float* Wo  = (const float*)d_in[9];
  const float* bo  = (const float*)d_in[10];
  const float* srk = (const float*)d_in[11];
  const float* srb = (const float*)d_in[12];
  const float* lng = (const float*)d_in[13];
  const float* lnb = (const float*)d_in[14];
  const float* tw  = (const float*)d_in[15];
  const float* bng = (const float*)d_in[17];
  const float* bnb = (const float*)d_in[18];
  float* out = (float*)d_out;
  const float QSC = 0.04419417382415922f;   // 1/sqrt(512)

  char* w = (char*)d_ws;
  size_t off = 0;
  auto alloc = [&](size_t bytes)->char*{
    char* p = w + off; off += (bytes + 255) & ~(size_t)255; return p;
  };

  const bool tierA = (ws_size >= (size_t)210*1024*1024);

  u16* Wqt = (u16*)alloc((size_t)HD_*C_*2);
  u16* Wkt = (u16*)alloc((size_t)HD_*C_*2);   // Wvt follows contiguously
  u16* Wvt = (u16*)alloc((size_t)HD_*C_*2);
  u16* Wot = (u16*)alloc((size_t)C_*HD_*2);
  u16* x   = (u16*)alloc((size_t)B_*NK_*C_*2 + 262144);     // +256K over-read pad
  float* bkv = (float*)alloc((size_t)2*HD_*4);              // bk || bv
  u16* Qin;
  u16* QfU;
  if(tierA){
    Qin = (u16*)alloc((size_t)B_*NQ_*C_*2);
    QfU = (u16*)alloc((size_t)B_*NQ_*HD_*2);
  } else {
    Qin = (u16*)alloc((size_t)NQ_*C_*2 + 262144);
    QfU = (u16*)alloc((size_t)NQ_*HD_*2);
  }
  u16* KV_b = (u16*)alloc((size_t)NK_*2*HD_*2 + 4194304);  // +4M: score B over-read
  u16* Vt_b = (u16*)alloc((size_t)HD_*NKP_*2);
  u16* S_b  = (u16*)alloc((size_t)8*NQ_*NKP_*2 + 524288);   // +512K PV A over-read pad
  float* colsum  = (float*)alloc((size_t)B_*HD_*4);
  float* partial = (float*)alloc((size_t)8*NQ_*4);
  float* aArr    = (float*)alloc(256);
  float* cArr    = (float*)alloc(256);
  float* corrB   = (float*)alloc((size_t)B_*C_*4);

  // ---- weight prep + conv+LN ----
  wt_kernel<<<dim3(128,16), 256, 0, stream>>>(Wq, Wqt, 512, 4096);
  wt_kernel<<<dim3(128,16), 256, 0, stream>>>(Wk, Wkt, 512, 4096);
  wt_kernel<<<dim3(128,16), 256, 0, stream>>>(Wv, Wvt, 512, 4096);
  wt_kernel<<<dim3(16,128), 256, 0, stream>>>(Wo, Wot, 4096, 512);
  conv_ln<<<B_*NK_, 256, 0, stream>>>(queries, srk, srb, lng, lnb, x);
  hipMemcpyAsync(bkv,      bk, HD_*4, hipMemcpyDeviceToDevice, stream);
  hipMemcpyAsync(bkv+HD_,  bv, HD_*4, hipMemcpyDeviceToDevice, stream);

  if(tierA){
    cvt_bf16<<<6272, 256, 0, stream>>>(queries, Qin, (long long)B_*NQ_*C_);
    // Qf = (queries@Wq + bq)/sqrt(512)
    gemm128<0><<<dim3(98,32,1),256,0,stream>>>(Qin, Wqt, QfU, B_*NQ_, 4096, 512,
        512, 512, HD_, 1, 0,0,0,0,0,0, bq, QSC, nullptr, nullptr, 1, 0);
  }

  for(int b=0; b<B_; b++){
    u16* Qf_b = tierA ? (QfU + (size_t)b*NQ_*HD_) : QfU;
    if(!tierA){
      cvt_bf16<<<1568, 256, 0, stream>>>(queries + (size_t)b*NQ_*C_, Qin, (long long)NQ_*C_);
      gemm128<0><<<dim3(25,32,1),256,0,stream>>>(Qin, Wqt, Qf_b, NQ_, 4096, 512,
          512, 512, HD_, 1, 0,0,0,0,0,0, bq, QSC, nullptr, nullptr, 1, 0);
    }
    const u16* x_b = x + (size_t)b*NK_*C_;
    // combined K|V projection: B spans Wkt..Wvt (adjacent, 8192 rows)
    gemm128<0><<<dim3(7,64,1),256,0,stream>>>(x_b, Wkt, KV_b, NK_, 2*HD_, 512,
        512, 512, 2*HD_, 1, 0,0,0,0,0,0, bkv, 1.0f, nullptr, nullptr, 1, 0);
    vt_kernel<<<dim3(26,128),256,0,stream>>>(KV_b + HD_, Vt_b, 2*HD_);
    colsum_v<<<16,256,0,stream>>>(KV_b + HD_, colsum + b*HD_, 2*HD_);
    // per-head scores: S_b[z] = Qf_b[:, z*512:+512] @ K_b[:, z*512:+512]^T
    gemm128<0><<<dim3(25,7,8),256,0,stream>>>(Qf_b, KV_b, S_b, NQ_, NKP_, 512,
        HD_, 2*HD_, NKP_, 8, 0, 512, 0, 512, 0, (long long)NQ_*NKP_,
        nullptr, 1.0f, nullptr, nullptr, 1, 0);
    mix_softmax<<<NQ_, 512, 0, stream>>>(S_b, tw, partial);
    finalize_stats<<<8,256,0,stream>>>(partial, bng + b*8, bnb + b*8, aArr + b*8, cArr + b*8);
    corr_kernel<<<512,256,0,stream>>>(colsum + b*HD_, Wot, cArr + b*8, corrB + b*C_);
    // U_b[:, z*512+d] = a[b,z] * (P~_z @ V_z)
    gemm128<0><<<dim3(25,4,8),256,0,stream>>>(S_b, Vt_b, Qf_b, NQ_, 512, NKP_,
        NKP_, NKP_, HD_, 8, 0, (long long)NQ_*NKP_, 0, (long long)512*NKP_, 0, 512,
        nullptr, 1.0f, aArr + b*8, nullptr, 1, 0);
    if(!tierA){
      gemm128<1><<<dim3(25,4,1),256,0,stream>>>(Qf_b, Wot, out + (size_t)b*NQ_*C_,
          NQ_, 512, HD_, HD_, HD_, C_,
          1, 0,0,0,0,0,0, bo, 1.0f, nullptr, corrB + b*C_, NQ_, C_);
    }
  }

  if(tierA){
    gemm128<1><<<dim3(98,4,1),256,0,stream>>>(QfU, Wot, out, B_*NQ_, 512, HD_,
        HD_, HD_, C_, 1, 0,0,0,0,0,0, bo, 1.0f, nullptr, corrB, NQ_, C_);
  }
}

// Round 9
// 910.759 us; speedup vs baseline: 2.8124x; 1.1063x over previous
//
#include <hip/hip_runtime.h>
#include <hip/hip_bf16.h>
#include <math.h>

typedef unsigned short u16;
typedef __attribute__((ext_vector_type(4))) float f32x4;
typedef __attribute__((ext_vector_type(8))) __bf16 bf16x8;

#define B_    4
#define NQ_   3136
#define C_    512
#define HIMG  56
#define WIMG  56
#define HD_   4096
#define NK_   784
#define NKP_  832

static __device__ __forceinline__ float b2f(u16 u){
  union { unsigned int i; float f; } v; v.i = ((unsigned int)u)<<16; return v.f;
}
static __device__ __forceinline__ u16 f2b(float f){
  union { float f; unsigned int i; } v; v.f = f;
  unsigned int r = v.i + 0x7fffu + ((v.i>>16)&1u);
  return (u16)(r>>16);
}

#define GLD16(gsrc, ldst) __builtin_amdgcn_global_load_lds( \
    (const __attribute__((address_space(1))) void*)(gsrc), \
    (__attribute__((address_space(3))) void*)(ldst), 16, 0, 0)

// ---------------------------------------------------------------------------
// L2-aware block ordering: XCD x (= hw id & 7, dispatch round-robin) owns a
// CONTIGUOUS range of the logical (bz-major, bx-mid, by-inner) block order.
// Effect: per XCD, A row-panel stays L2-resident and each B slab is read once
// (by-inner reuses the A slab; bx-panel bounds the A working set).
// For nz==8 grids each XCD gets exactly one z slice.
// Requires n%8==0 for the partition (all our grids satisfy); else identity.
// ---------------------------------------------------------------------------
static __device__ __forceinline__ void xcd_order(int &bx, int &by, int &bz){
  const int nx = gridDim.x, ny = gridDim.y, nz = gridDim.z;
  long l = blockIdx.x + (long)nx*(blockIdx.y + (long)ny*blockIdx.z);
  const long n = (long)nx*ny*nz;
  long g = ((n&7)==0) ? ((l&7)*(n>>3) + (l>>3)) : l;
  by = (int)(g % ny); g /= ny;
  bx = (int)(g % nx);
  bz = (int)(g / nx);
}

// ---------------------------------------------------------------------------
// 128x128 4-wave bf16 GEMM v5: BK=32, 4-buffer LDS ring, prefetch depth 3
// (~3 tiles of compute >= HBM latency), counted vmcnt(8), 1 barrier/tile,
// 64 KiB LDS -> 2 blocks/CU, XOR swizzle for 64B rows.
// C[m,n] = (sum_k A[m,k]*B[n,k] + bias1[n]) * hscale * scalePtr[z] (+bias2).
// A:(M,K) stride sA; B:(N,K) stride sB. Waves 2x2, wave tile 64x64.
// Tile j (buf=j&3):
//   vmcnt(8|4|0 tail); s_barrier     -> tile j in LDS; buf (j+3)&3 is free
//   8x ds_read_b128 (af[4],bf[4]); STAGE(j+3 -> (j+3)&3);
//   setprio(1) 16 MFMA setprio(0)
// ds_read completion before the next barrier is guaranteed by each wave's own
// MFMA lgkmcnt; staged loads are consumed 3 tiles later via the counted vmcnt.
// Swizzle: LDS[row][c] holds source chunk c^((row>>1)&3) (8-elem chunks);
// staging pre-swizzles the global source column, reads XOR the chunk index.
// Verified balanced: 8 lanes per 4-bank group per b128 wave-read.
// Loads NOT masked (caller guarantees over-read slack); stores masked.
// Requires K%32==0, K>=96.
// ---------------------------------------------------------------------------
template<int OUT_F32>
__global__ __launch_bounds__(256)
void gemm128(const u16* __restrict__ A, const u16* __restrict__ Bm, void* __restrict__ Cm,
             int M, int Ncols, int K, int sA, int sB, int sC, int zdiv,
             long long zA1, long long zA2, long long zB1, long long zB2,
             long long zC1, long long zC2,
             const float* __restrict__ bias1, float hscale,
             const float* __restrict__ scalePtr,
             const float* __restrict__ bias2, int rowsPerB, int b2s)
{
  __shared__ u16 lds[32768];     // 64 KiB: A 4x8K @0, B 4x8K @32K (bytes)
  int bx, by, z;
  xcd_order(bx, by, z);
  const int zq = z / zdiv, zr = z % zdiv;
  const u16* Ab = A  + (long long)zq*zA1 + (long long)zr*zA2;
  const u16* Bb = Bm + (long long)zq*zB1 + (long long)zr*zB2;
  const int m0 = bx*128, n0 = by*128;
  const int t = threadIdx.x, w = t>>6, lane = t&63;
  const int wm = w>>1, wn = w&1;             // 2 x 2 wave grid
  const int l15 = lane & 15;

  // staging: 4 threads/row, 64 rows per GLD16 group; pre-swizzled source col
  const int srow = t>>2;                                   // 0..63
  const int scol = (((t&3) ^ ((srow>>1)&3)) << 3);         // elems (chunk of 8)
  const u16* aS = Ab + (long long)(m0 + srow)*sA + scol;
  const u16* bS = Bb + (long long)(n0 + srow)*sB + scol;
  const long long sA64 = (long long)64*sA, sB64 = (long long)64*sB;
  const int w512 = w*512;                                  // u16 units (1 KB)

#define STAGE(jt, buf) do{                                        \
    const u16* a0_ = aS + (long long)(jt)*32;                     \
    const u16* b0_ = bS + (long long)(jt)*32;                     \
    u16* la_ = lds + (buf)*4096 + w512;                           \
    u16* lb_ = lds + 16384 + (buf)*4096 + w512;                   \
    GLD16(a0_,          la_);                                     \
    GLD16(a0_ + sA64,   la_ + 2048);                              \
    GLD16(b0_,          lb_);                                     \
    GLD16(b0_ + sB64,   lb_ + 2048);                              \
  }while(0)

  f32x4 acc[4][4];
#pragma unroll
  for(int i=0;i<4;i++)
#pragma unroll
    for(int j=0;j<4;j++) acc[i][j] = (f32x4)(0.0f);

  const char* ldsc = (const char*)lds;
  const int ck = (((lane>>4) ^ ((lane>>1)&3)) << 4);   // swizzled chunk (bytes)
  const int aRowB = (wm*64 + l15) * 64;                // A row byte base (64B rows)
  const int bRowB = (wn*64 + l15) * 64;

  const int T = K >> 5;
  STAGE(0, 0);
  STAGE(1, 1);
  STAGE(2, 2);

  for(int j=0; j<T; j++){
    const int buf = j & 3;
    if(j+2 < T)      asm volatile("s_waitcnt vmcnt(8)" ::: "memory");
    else if(j+1 < T) asm volatile("s_waitcnt vmcnt(4)" ::: "memory");
    else             asm volatile("s_waitcnt vmcnt(0)" ::: "memory");
    asm volatile("s_barrier" ::: "memory");   // tile j visible; buf (j+3)&3 free

    const int aBuf = buf*8192 + aRowB;
    const int bBuf = 32768 + buf*8192 + bRowB;
    bf16x8 af[4], bfv[4];
#pragma unroll
    for(int fr=0; fr<4; fr++) af[fr]  = *(const bf16x8*)(ldsc + aBuf + fr*1024 + ck);
#pragma unroll
    for(int fn=0; fn<4; fn++) bfv[fn] = *(const bf16x8*)(ldsc + bBuf + fn*1024 + ck);
    if(j+3 < T) STAGE(j+3, (j+3)&3);
    __builtin_amdgcn_s_setprio(1);
#pragma unroll
    for(int fr=0; fr<4; fr++)
#pragma unroll
      for(int fn=0; fn<4; fn++)
        acc[fr][fn] = __builtin_amdgcn_mfma_f32_16x16x32_bf16(af[fr], bfv[fn], acc[fr][fn], 0,0,0);
    __builtin_amdgcn_s_setprio(0);
  }
#undef STAGE

  const float dsc = scalePtr ? scalePtr[z] : 1.0f;
  const long long cBase = (long long)zq*zC1 + (long long)zr*zC2;
  const int r4 = (lane>>4)*4;
#pragma unroll
  for(int mf=0; mf<4; mf++){
    const int row0 = m0 + wm*64 + mf*16 + r4;
#pragma unroll
    for(int nf=0; nf<4; nf++){
      const int col = n0 + wn*64 + nf*16 + l15;
      if(col < Ncols){
#pragma unroll
        for(int r=0;r<4;r++){
          const int row = row0 + r;
          if(row < M){
            float v = acc[mf][nf][r];
            if(bias1) v += bias1[col];
            v *= hscale * dsc;
            if(bias2) v += bias2[(row/rowsPerB)*b2s + col];
            if(OUT_F32) ((float*)Cm)[cBase + (long long)row*sC + col] = v;
            else        ((u16*) Cm)[cBase + (long long)row*sC + col] = f2b(v);
          }
        }
      }
    }
  }
}

// f32 (K,N) weight -> bf16 (N,K) transpose
__global__ __launch_bounds__(256)
void wt_kernel(const float* __restrict__ W, u16* __restrict__ Wt, int K, int N){
  __shared__ float tile[32][33];
  const int n0 = blockIdx.x*32, k0 = blockIdx.y*32;
  const int t = threadIdx.x, tr = t>>5, tc = t&31;
#pragma unroll
  for(int i=0;i<4;i++)
    tile[tr+i*8][tc] = W[(long long)(k0+tr+i*8)*N + n0+tc];
  __syncthreads();
#pragma unroll
  for(int i=0;i<4;i++)
    Wt[(long long)(n0+tr+i*8)*K + k0+tc] = f2b(tile[tc][tr+i*8]);
}

__global__ __launch_bounds__(256)
void cvt_bf16(const float* __restrict__ in, u16* __restrict__ outp, long long n){
  long long i = ((long long)blockIdx.x*256 + threadIdx.x)*4;
  if(i+3 < n){
    float4 v = *(const float4*)(in+i);
    ushort4 o; o.x=f2b(v.x); o.y=f2b(v.y); o.z=f2b(v.z); o.w=f2b(v.w);
    *(ushort4*)(outp+i) = o;
  }
}

// depthwise 3x3 stride-2 SAME conv (pad lo=0,hi=1) + bias + LayerNorm -> bf16
__global__ __launch_bounds__(256)
void conv_ln(const float* __restrict__ q, const float* __restrict__ ker,
             const float* __restrict__ cbias, const float* __restrict__ gamma,
             const float* __restrict__ beta, u16* __restrict__ xo)
{
  const int p = blockIdx.x;
  const int b = p / 784, pix = p % 784;
  const int oy = pix / 28, ox = pix % 28;
  const int t = threadIdx.x;
  __shared__ float red[256];
  float v[2];
#pragma unroll
  for(int e=0;e<2;e++){
    const int c = t + e*256;
    float acc = cbias[c];
    for(int ky=0;ky<3;ky++){
      const int y = oy*2 + ky;
      if(y >= HIMG) continue;
      for(int kx=0;kx<3;kx++){
        const int x = ox*2 + kx;
        if(x >= WIMG) continue;
        acc += q[(((long long)b*HIMG + y)*WIMG + x)*C_ + c] * ker[(ky*3+kx)*C_ + c];
      }
    }
    v[e] = acc;
  }
  red[t]=v[0]+v[1]; __syncthreads();
  for(int st=128; st>0; st>>=1){ if(t<st) red[t]+=red[t+st]; __syncthreads(); }
  const float mu = red[0] * (1.0f/C_);
  __syncthreads();
  const float d0=v[0]-mu, d1=v[1]-mu;
  red[t]=d0*d0+d1*d1; __syncthreads();
  for(int st=128; st>0; st>>=1){ if(t<st) red[t]+=red[t+st]; __syncthreads(); }
  const float rs = rsqrtf(red[0]*(1.0f/C_) + 1e-3f);
  const long long ob = (long long)p*C_;
#pragma unroll
  for(int e=0;e<2;e++){
    const int c = t+e*256;
    xo[ob+c] = f2b((v[e]-mu)*rs*gamma[c] + beta[c]);
  }
}

// per-batch: V part of KV_b (784 x 4096, row stride sV) -> Vt_b (4096,832), k zero-padded
__global__ __launch_bounds__(256)
void vt_kernel(const u16* __restrict__ Vf_b, u16* __restrict__ Vt_b, int sV){
  __shared__ u16 tile[32][33];
  const int k0 = blockIdx.x*32, d0 = blockIdx.y*32;
  const int t = threadIdx.x, tr = t>>5, tc = t&31;
#pragma unroll
  for(int i=0;i<4;i++){
    const int k = k0+tr+i*8;
    tile[tr+i*8][tc] = (k < NK_) ? Vf_b[(long long)k*sV + d0+tc] : (u16)0;
  }
  __syncthreads();
#pragma unroll
  for(int i=0;i<4;i++)
    Vt_b[(long long)(d0+tr+i*8)*NKP_ + k0+tc] = tile[tc][tr+i*8];
}

// ---------------------------------------------------------------------------
// Wave-parallel mix+softmax: one block (512 thr = 8 waves) per q-row.
// Unique-slot partial sums (no hot atomics). Zeroes pad cols 784..831.
// ---------------------------------------------------------------------------
__global__ __launch_bounds__(512)
void mix_softmax(u16* __restrict__ S_b, const float* __restrict__ tw,
                 float* __restrict__ partial_b)
{
  const int qi = blockIdx.x;
  const int t = threadIdx.x;
  const int wave = t >> 6, lane = t & 63;
  __shared__ float sv[8*NK_];
  const long long rowstr = (long long)NQ_*NKP_;
  const long long base = (long long)qi*NKP_;

  for(int idx = t; idx < 8*196; idx += 512){
    const int h = idx / 196, c4 = idx % 196;
    ushort4 u4 = *(const ushort4*)(S_b + base + h*rowstr + c4*4);
    float* d = sv + h*NK_ + c4*4;
    d[0]=b2f(u4.x); d[1]=b2f(u4.y); d[2]=b2f(u4.z); d[3]=b2f(u4.w);
  }
  __syncthreads();

  const int g = wave;
  float wgt[8];
#pragma unroll
  for(int h=0;h<8;h++) wgt[h] = tw[h*8+g];

  float xs[13];
  float lmax = -1e30f;
#pragma unroll
  for(int j=0;j<13;j++){
    const int k = j*64 + lane;
    if(k < NK_){
      float x = 0.f;
#pragma unroll
      for(int h=0;h<8;h++) x += wgt[h]*sv[h*NK_+k];
      xs[j] = x;
      lmax = fmaxf(lmax, x);
    } else xs[j] = -1e30f;
  }
#pragma unroll
  for(int off=32; off>=1; off>>=1) lmax = fmaxf(lmax, __shfl_xor(lmax, off));

  float lsum = 0.f;
#pragma unroll
  for(int j=0;j<13;j++){
    const int k = j*64 + lane;
    if(k < NK_){
      const float e = __expf(xs[j] - lmax);
      xs[j] = e; lsum += e;
    }
  }
#pragma unroll
  for(int off=32; off>=1; off>>=1) lsum += __shfl_xor(lsum, off);
  const float inv = 1.0f/lsum;

  u16* dst = S_b + base + g*rowstr;
  float lss = 0.f;
#pragma unroll
  for(int j=0;j<13;j++){
    const int k = j*64 + lane;
    if(k < NK_){
      const float dev = xs[j]*inv - (1.0f/NK_);
      dst[k] = f2b(dev);
      lss += dev*dev;
    }
  }
  for(int k = NK_ + lane; k < NKP_; k += 64) dst[k] = 0;
#pragma unroll
  for(int off=32; off>=1; off>>=1) lss += __shfl_xor(lss, off);
  if(lane==0) partial_b[g*NQ_ + qi] = lss;
}

// column sums of V, k-split into 8 chunks of 98 -> part[kc][hd]
__global__ __launch_bounds__(256)
void colsum_v(const u16* __restrict__ Vf_b, float* __restrict__ part, int sV){
  const int hd = blockIdx.x*256 + threadIdx.x;
  const int kc = blockIdx.y;
  const u16* p = Vf_b + (long long)kc*98*sV + hd;
  float s=0.f;
  for(int k=0;k<98;k++) s += b2f(p[(long long)k*sV]);
  part[(long long)kc*HD_ + hd] = s;
}

__global__ __launch_bounds__(256)
void finalize_stats(const float* __restrict__ partial_b, const float* __restrict__ bng_b,
                    const float* __restrict__ bnb_b, float* __restrict__ a_b,
                    float* __restrict__ c_b){
  const int g = blockIdx.x;
  const int t = threadIdx.x;
  __shared__ float red[4];
  float s = 0.f;
  for(int i=t; i<NQ_; i+=256) s += partial_b[g*NQ_ + i];
#pragma unroll
  for(int off=32; off>=1; off>>=1) s += __shfl_xor(s, off);
  if((t&63)==0) red[t>>6] = s;
  __syncthreads();
  if(t==0){
    const float tot = red[0]+red[1]+red[2]+red[3];
    const float s2 = tot * (1.0f/((float)NQ_*(float)NK_));
    a_b[g] = bng_b[g]*rsqrtf(s2 + 1e-3f);
    c_b[g] = bnb_b[g];
  }
}

// corr_b[n] = sum_g c_b[g] * (colsumV_b[g*512:(g+1)*512] . Wo_g[:,n])
// colsum comes k-split: sum 8 partial rows.
__global__ __launch_bounds__(256)
void corr_kernel(const float* __restrict__ part, const u16* __restrict__ Wot,
                 const float* __restrict__ c_b, float* __restrict__ corr_b){
  const int n = blockIdx.x, t = threadIdx.x;
  __shared__ float red[256];
  float s = 0.f;
  for(int hd=t; hd<HD_; hd+=256){
    float cs = 0.f;
#pragma unroll
    for(int kc=0; kc<8; kc++) cs += part[(long long)kc*HD_ + hd];
    s += c_b[hd>>9] * cs * b2f(Wot[(long long)n*HD_+hd]);
  }
  red[t]=s; __syncthreads();
  for(int st=128; st>0; st>>=1){ if(t<st) red[t]+=red[t+st]; __syncthreads(); }
  if(t==0) corr_b[n]=red[0];
}

// ---------------------------------------------------------------------------
extern "C" void kernel_launch(void* const* d_in, const int* in_sizes, int n_in,
                              void* d_out, int out_size, void* d_ws, size_t ws_size,
                              hipStream_t stream)
{
  (void)in_sizes; (void)n_in; (void)out_size;
  const float* queries = (const float*)d_in[0];
  const float* Wq  = (const float*)d_in[3];
  const float* bq  = (const float*)d_in[4];
  const float* Wk  = (const float*)d_in[5];
  const float* bk  = (const float*)d_in[6];
  const float* Wv  = (const float*)d_in[7];
  const float* bv  = (const float*)d_in[8];
  const float* Wo  = (const float*)d_in[9];
  const float* bo  = (const float*)d_in[10];
  const float* srk = (const float*)d_in[11];
  const float* srb = (const float*)d_in[12];
  const float* lng = (const float*)d_in[13];
  const float* lnb = (const float*)d_in[14];
  const float* tw  = (const float*)d_in[15];
  const float* bng = (const float*)d_in[17];
  const float* bnb = (const float*)d_in[18];
  float* out = (float*)d_out;
  const float QSC = 0.04419417382415922f;   // 1/sqrt(512)

  char* w = (char*)d_ws;
  size_t off = 0;
  auto alloc = [&](size_t bytes)->char*{
    char* p = w + off; off += (bytes + 255) & ~(size_t)255; return p;
  };

  const bool tierA = (ws_size >= (size_t)210*1024*1024);

  u16* Wqt = (u16*)alloc((size_t)HD_*C_*2);
  u16* Wkt = (u16*)alloc((size_t)HD_*C_*2);   // Wvt follows contiguously
  u16* Wvt = (u16*)alloc((size_t)HD_*C_*2);
  u16* Wot = (u16*)alloc((size_t)C_*HD_*2);
  u16* x   = (u16*)alloc((size_t)B_*NK_*C_*2 + 262144);     // +256K over-read pad
  float* bkv = (float*)alloc((size_t)2*HD_*4);              // bk || bv
  u16* Qin;
  u16* QfU;
  if(tierA){
    Qin = (u16*)alloc((size_t)B_*NQ_*C_*2);
    QfU = (u16*)alloc((size_t)B_*NQ_*HD_*2);
  } else {
    Qin = (u16*)alloc((size_t)NQ_*C_*2 + 262144);
    QfU = (u16*)alloc((size_t)NQ_*HD_*2);
  }
  u16* KV_b = (u16*)alloc((size_t)NK_*2*HD_*2 + 4194304);  // +4M: score B over-read
  u16* Vt_b = (u16*)alloc((size_t)HD_*NKP_*2);
  u16* S_b  = (u16*)alloc((size_t)8*NQ_*NKP_*2 + 524288);   // +512K PV A over-read pad
  float* colsum  = (float*)alloc((size_t)8*HD_*4);          // k-split partials (per batch)
  float* partial = (float*)alloc((size_t)8*NQ_*4);
  float* aArr    = (float*)alloc(256);
  float* cArr    = (float*)alloc(256);
  float* corrB   = (float*)alloc((size_t)B_*C_*4);

  // ---- weight prep + conv+LN ----
  wt_kernel<<<dim3(128,16), 256, 0, stream>>>(Wq, Wqt, 512, 4096);
  wt_kernel<<<dim3(128,16), 256, 0, stream>>>(Wk, Wkt, 512, 4096);
  wt_kernel<<<dim3(128,16), 256, 0, stream>>>(Wv, Wvt, 512, 4096);
  wt_kernel<<<dim3(16,128), 256, 0, stream>>>(Wo, Wot, 4096, 512);
  conv_ln<<<B_*NK_, 256, 0, stream>>>(queries, srk, srb, lng, lnb, x);
  hipMemcpyAsync(bkv,      bk, HD_*4, hipMemcpyDeviceToDevice, stream);
  hipMemcpyAsync(bkv+HD_,  bv, HD_*4, hipMemcpyDeviceToDevice, stream);

  if(tierA){
    cvt_bf16<<<6272, 256, 0, stream>>>(queries, Qin, (long long)B_*NQ_*C_);
    // Qf = (queries@Wq + bq)/sqrt(512)
    gemm128<0><<<dim3(98,32,1),256,0,stream>>>(Qin, Wqt, QfU, B_*NQ_, 4096, 512,
        512, 512, HD_, 1, 0,0,0,0,0,0, bq, QSC, nullptr, nullptr, 1, 0);
  }

  for(int b=0; b<B_; b++){
    u16* Qf_b = tierA ? (QfU + (size_t)b*NQ_*HD_) : QfU;
    if(!tierA){
      cvt_bf16<<<1568, 256, 0, stream>>>(queries + (size_t)b*NQ_*C_, Qin, (long long)NQ_*C_);
      gemm128<0><<<dim3(25,32,1),256,0,stream>>>(Qin, Wqt, Qf_b, NQ_, 4096, 512,
          512, 512, HD_, 1, 0,0,0,0,0,0, bq, QSC, nullptr, nullptr, 1, 0);
    }
    const u16* x_b = x + (size_t)b*NK_*C_;
    // combined K|V projection: B spans Wkt..Wvt (adjacent, 8192 rows)
    gemm128<0><<<dim3(7,64,1),256,0,stream>>>(x_b, Wkt, KV_b, NK_, 2*HD_, 512,
        512, 512, 2*HD_, 1, 0,0,0,0,0,0, bkv, 1.0f, nullptr, nullptr, 1, 0);
    vt_kernel<<<dim3(26,128),256,0,stream>>>(KV_b + HD_, Vt_b, 2*HD_);
    colsum_v<<<dim3(16,8),256,0,stream>>>(KV_b + HD_, colsum, 2*HD_);
    // per-head scores: S_b[z] = Qf_b[:, z*512:+512] @ K_b[:, z*512:+512]^T
    gemm128<0><<<dim3(25,7,8),256,0,stream>>>(Qf_b, KV_b, S_b, NQ_, NKP_, 512,
        HD_, 2*HD_, NKP_, 8, 0, 512, 0, 512, 0, (long long)NQ_*NKP_,
        nullptr, 1.0f, nullptr, nullptr, 1, 0);
    mix_softmax<<<NQ_, 512, 0, stream>>>(S_b, tw, partial);
    finalize_stats<<<8,256,0,stream>>>(partial, bng + b*8, bnb + b*8, aArr + b*8, cArr + b*8);
    corr_kernel<<<512,256,0,stream>>>(colsum, Wot, cArr + b*8, corrB + b*C_);
    // U_b[:, z*512+d] = a[b,z] * (P~_z @ V_z)
    gemm128<0><<<dim3(25,4,8),256,0,stream>>>(S_b, Vt_b, Qf_b, NQ_, 512, NKP_,
        NKP_, NKP_, HD_, 8, 0, (long long)NQ_*NKP_, 0, (long long)512*NKP_, 0, 512,
        nullptr, 1.0f, aArr + b*8, nullptr, 1, 0);
    if(!tierA){
      gemm128<1><<<dim3(25,4,1),256,0,stream>>>(Qf_b, Wot, out + (size_t)b*NQ_*C_,
          NQ_, 512, HD_, HD_, HD_, C_,
          1, 0,0,0,0,0,0, bo, 1.0f, nullptr, corrB + b*C_, NQ_, C_);
    }
  }

  if(tierA){
    gemm128<1><<<dim3(98,4,1),256,0,stream>>>(QfU, Wot, out, B_*NQ_, 512, HD_,
        HD_, HD_, C_, 1, 0,0,0,0,0,0, bo, 1.0f, nullptr, corrB, NQ_, C_);
  }
}